// Round 16
// baseline (1384.541 us; speedup 1.0000x reference)
//
#include <hip/hip_runtime.h>
#include <hip/hip_bf16.h>

typedef __hip_bfloat16 bf16;
typedef __attribute__((ext_vector_type(8))) short bf16x8;
typedef __attribute__((ext_vector_type(4))) float f32x4;

// ---------- helpers ----------
__device__ __forceinline__ float b2f(bf16 v){ return __bfloat162float(v); }
__device__ __forceinline__ bf16 f2b(float v){ return __float2bfloat16(v); }
__device__ __forceinline__ float bits2f(unsigned u){ return __uint_as_float(u << 16); }
__device__ __forceinline__ unsigned short f2bits(float v){ bf16 t = __float2bfloat16(v); return *(unsigned short*)&t; }

__device__ __forceinline__ float gelu_f(float x){
  return 0.5f * x * (1.f + erff(x * 0.7071067811865475f));
}

__device__ __forceinline__ void gload_lds(const void* g, void* l){
  __builtin_amdgcn_global_load_lds((const __attribute__((address_space(1))) void*)g,
                                   (__attribute__((address_space(3))) void*)l, 16, 0, 0);
}

template<bool MAX>
__device__ __forceinline__ float block_reduce(float v){
  __shared__ float s[4];
  #pragma unroll
  for (int o = 32; o > 0; o >>= 1){
    float t = __shfl_down(v, o, 64);
    v = MAX ? fmaxf(v, t) : (v + t);
  }
  int lane = threadIdx.x & 63, w = threadIdx.x >> 6;
  __syncthreads();
  if (lane == 0) s[w] = v;
  __syncthreads();
  return MAX ? fmaxf(fmaxf(s[0], s[1]), fmaxf(s[2], s[3]))
             : (s[0] + s[1] + s[2] + s[3]);
}

// ---------- dtype detect + converters ----------
__global__ void detect_k(const unsigned* __restrict__ x, int* __restrict__ flag){
  __shared__ int cnt[256];
  int tid = threadIdx.x;
  int c = 0;
  for (int i = tid; i < 4096; i += 256){
    unsigned h = x[i] & 0xffffu;
    int e = (int)((h >> 7) & 0xff);
    if (h == 0u || (e >= 100 && e <= 133)) c++;
  }
  cnt[tid] = c;
  __syncthreads();
  for (int o = 128; o > 0; o >>= 1){ if (tid < o) cnt[tid] += cnt[tid+o]; __syncthreads(); }
  if (tid == 0) *flag = (cnt[0] < 2048) ? 1 : 0;
}

__global__ __launch_bounds__(256) void cvt_x_k(const void* __restrict__ src,
                                               float* __restrict__ X,
                                               const int* __restrict__ flag){
  int p = blockIdx.x*256 + threadIdx.x;
  X[p] = (*flag) ? ((const float*)src)[p]
                 : __bfloat162float(((const bf16*)src)[p]);
}

struct WCvt21 { const void* src[21]; long long cum[22]; };

__global__ __launch_bounds__(256) void cvt_w_k(WCvt21 a, bf16* __restrict__ WB,
                                               long long total, const int* __restrict__ flag){
  long long i = (long long)blockIdx.x*256 + threadIdx.x;
  if (i >= total) return;
  int t = 0;
  while (a.cum[t+1] <= i) t++;
  long long e = i - a.cum[t];
  WB[i] = (*flag) ? __float2bfloat16(((const float*)a.src[t])[e])
                  : ((const bf16*)a.src[t])[e];
}

// transpose + convert weight: dst[z][c][r] = src[z][r][c], tiles 64x64
__global__ __launch_bounds__(256) void wtrans_k(const void* __restrict__ src, bf16* __restrict__ dst,
                                                int ld_src, int ldd, long long sSrc, long long sDst,
                                                const int* __restrict__ flag){
  __shared__ bf16 t[64][65];
  int z = blockIdx.z;
  int r0 = blockIdx.x*64, c0 = blockIdx.y*64;
  int lane = threadIdx.x & 63, quad = threadIdx.x >> 6;
  const float* sf = (const float*)src;
  const bf16* sb = (const bf16*)src;
  int fl = *flag;
  #pragma unroll
  for (int k = 0; k < 16; ++k){
    int r = quad*16 + k;
    long long idx = z*sSrc + (long long)(r0+r)*ld_src + c0 + lane;
    float v = fl ? sf[idx] : b2f(sb[idx]);
    t[r][lane] = f2b(v);
  }
  __syncthreads();
  #pragma unroll
  for (int k = 0; k < 16; ++k){
    int c = quad*16 + k;
    dst[z*sDst + (long long)(c0+c)*ldd + r0 + lane] = t[lane][c];
  }
}

// conv-attn weight shuffle: Wr[l][16][96]; Wr[l][ho][tap*8+hi] = spw[l][ho][hi][tap], 0-padded
__global__ void wprep_k(const bf16* __restrict__ spw, bf16* __restrict__ Wr){
  int l = blockIdx.x;
  for (int t = threadIdx.x; t < 1536; t += 256){
    int ho = t / 96, k = t - ho*96;
    float v = 0.f;
    if (ho < 8 && k < 72){
      int tap = k >> 3, hi = k & 7;
      v = b2f(spw[l*576 + ho*72 + hi*9 + tap]);
    }
    Wr[l*1536 + t] = f2b(v);
  }
}

__global__ __launch_bounds__(256) void store_out_k(const float* __restrict__ X,
                                                   void* __restrict__ out,
                                                   const int* __restrict__ flag){
  int p = blockIdx.x*256 + threadIdx.x;
  if (*flag) ((float*)out)[p] = X[p];
  else       ((bf16*)out)[p] = f2b(X[p]);
}

__global__ __launch_bounds__(256) void zero_k(float* __restrict__ p, int n){
  int i = blockIdx.x*256 + threadIdx.x;
  if (i < n) p[i] = 0.f;
}

// ---------- MFMA GEMM ----------
// C[z] = epi( alpha * A(MxK,row) x Bt(NxK,row)^T ); z decomposes as (z&7, z>>3)
// EXP=1: C = exp(alpha*acc) (bf16/f32), row sums atomically added to srow.
template<int MF, int NF, typename TC, int EXP>
__global__ __launch_bounds__(256) void gmfma_k(
    int M, int N, int K,
    const bf16* __restrict__ A, int lda, long long sA, long long sA2,
    const bf16* __restrict__ Bt, int ldb, long long sB, long long sB2,
    TC* __restrict__ C, int ldc, long long sC, long long sC2,
    float alpha, int beta,
    const bf16* __restrict__ bias_n,
    const float* __restrict__ scale_n,
    const float* __restrict__ shift_n,
    const bf16* __restrict__ addF,
    int act,
    bf16* __restrict__ vt,
    float* __restrict__ srow, long long szl, long long szh, long long sgm)
{
  constexpr int BM = MF*32, BN = NF*32;
  constexpr int CHA = BM/16, CH = (BM+BN)/16;
  static_assert(CH % 4 == 0, "chunks must divide among 4 waves");
  __shared__ bf16 Asm[BM][32];
  __shared__ bf16 Bsm[BN][32];
  const int tid = threadIdx.x;
  const int lane = tid & 63, wid = tid >> 6;
  const int wm = wid >> 1, wn = wid & 1;
  const int m0 = blockIdx.y*BM, n0 = blockIdx.x*BN;
  const int z = blockIdx.z;
  const long long zl = z & 7, zh = z >> 3;
  const bf16* Ab = A + zl*sA + zh*sA2;
  const bf16* Bb = Bt + zl*sB + zh*sB2;
  TC* Cb = C + zl*sC + zh*sC2;
  const bf16* Fb = addF ? addF + zl*sC + zh*sC2 : nullptr;

  f32x4 acc[MF][NF];
  f32x4 zero = {0.f, 0.f, 0.f, 0.f};
  #pragma unroll
  for (int m = 0; m < MF; ++m)
    #pragma unroll
    for (int n = 0; n < NF; ++n) acc[m][n] = zero;

  const int rchunk = lane >> 2;
  const int kchunk = (lane & 3) * 8;
  const int row16 = lane & 15, kq = (lane >> 4) * 8;

  for (int k0 = 0; k0 < K; k0 += 32){
    #pragma unroll
    for (int cc = 0; cc < CH/4; ++cc){
      int c = wid + cc*4;
      if (c < CHA){
        int row = c*16 + rchunk;
        gload_lds(Ab + (long long)(m0+row)*lda + k0 + kchunk, &Asm[c*16][0]);
      } else {
        int row = (c-CHA)*16 + rchunk;
        gload_lds(Bb + (long long)(n0+row)*ldb + k0 + kchunk, &Bsm[(c-CHA)*16][0]);
      }
    }
    __syncthreads();
    bf16x8 af[MF], bfr[NF];
    #pragma unroll
    for (int m = 0; m < MF; ++m)
      af[m] = *(const bf16x8*)&Asm[wm*(MF*16) + m*16 + row16][kq];
    #pragma unroll
    for (int n = 0; n < NF; ++n)
      bfr[n] = *(const bf16x8*)&Bsm[wn*(NF*16) + n*16 + row16][kq];
    #pragma unroll
    for (int m = 0; m < MF; ++m)
      #pragma unroll
      for (int n = 0; n < NF; ++n)
        acc[m][n] = __builtin_amdgcn_mfma_f32_16x16x32_bf16(af[m], bfr[n], acc[m][n], 0, 0, 0);
    __syncthreads();
  }

  if constexpr (EXP){
    // e = exp(alpha*acc); store; butterfly row-sum over lane&15; atomicAdd per row.
    #pragma unroll
    for (int m = 0; m < MF; ++m){
      int gmb = m0 + wm*(MF*16) + m*16 + (lane >> 4)*4;
      float rowsum[4] = {0.f, 0.f, 0.f, 0.f};
      #pragma unroll
      for (int n = 0; n < NF; ++n){
        int gn = n0 + wn*(NF*16) + n*16 + row16;
        #pragma unroll
        for (int r = 0; r < 4; ++r){
          float e = __expf(acc[m][n][r] * alpha);
          long long idx = (long long)(gmb + r)*ldc + gn;
          if constexpr (__is_same(TC, float)) Cb[idx] = e; else Cb[idx] = f2b(e);
          rowsum[r] += e;
        }
      }
      #pragma unroll
      for (int r = 0; r < 4; ++r){
        float s = rowsum[r];
        #pragma unroll
        for (int o = 1; o < 16; o <<= 1) s += __shfl_xor(s, o, 64);
        if ((lane & 15) == 0)
          atomicAdd(&srow[zl*szl + zh*szh + (long long)(gmb + r)*sgm], s);
      }
    }
    return;
  }

  #pragma unroll
  for (int m = 0; m < MF; ++m){
    #pragma unroll
    for (int n = 0; n < NF; ++n){
      int gn = n0 + wn*(NF*16) + n*16 + row16;
      float bn_ = bias_n ? b2f(bias_n[gn]) : 0.f;
      float sc = scale_n ? scale_n[gn] : 1.f;
      float sh = shift_n ? shift_n[gn] : 0.f;
      int gmb = m0 + wm*(MF*16) + m*16 + (lane >> 4)*4;
      float vals[4];
      #pragma unroll
      for (int r = 0; r < 4; ++r){
        int gm = gmb + r;
        float v = acc[m][n][r] * alpha + bn_;
        v = v * sc + sh;
        if (act) v = gelu_f(v);
        long long idx = (long long)gm*ldc + gn;
        if (Fb) v += b2f(Fb[idx]);
        if (beta){
          float old;
          if constexpr (__is_same(TC, float)) old = Cb[idx]; else old = b2f(Cb[idx]);
          v += old;
        }
        if constexpr (__is_same(TC, float)) Cb[idx] = v; else Cb[idx] = f2b(v);
        vals[r] = v;
      }
      if (vt && gn >= 1024){
        int h = (gn - 1024) >> 6, d = (gn - 1024) & 63;
        int bb = gmb >> 10, nn = gmb & 1023;
        ushort4 o;
        o.x = f2bits(vals[0]); o.y = f2bits(vals[1]);
        o.z = f2bits(vals[2]); o.w = f2bits(vals[3]);
        *(ushort4*)&vt[(((long long)bb*8 + h)*64 + d)*1024 + nn] = o;
      }
    }
  }
}

template<int MF, int NF, typename TC>
static void gmfma_x(hipStream_t st, int z, int M, int N, int K,
                    const bf16* A, int lda, long long sA, long long sA2,
                    const bf16* Bt, int ldb, long long sB, long long sB2,
                    TC* C, int ldc, long long sC, long long sC2,
                    float alpha = 1.f, int beta = 0,
                    const bf16* bias_n = nullptr,
                    const float* scale_n = nullptr, const float* shift_n = nullptr,
                    const bf16* addF = nullptr, int act = 0, bf16* vt = nullptr)
{
  dim3 g(N/(NF*32), M/(MF*32), z);
  gmfma_k<MF,NF,TC,0><<<g, 256, 0, st>>>(M,N,K,A,lda,sA,sA2,Bt,ldb,sB,sB2,C,ldc,sC,sC2,
                                         alpha,beta,bias_n,scale_n,shift_n,addF,act,vt,
                                         nullptr,0,0,0);
}

template<int MF, int NF, typename TC>
static void gmfma(hipStream_t st, int z, int M, int N, int K,
                  const bf16* A, int lda, long long sA,
                  const bf16* Bt, int ldb, long long sB,
                  TC* C, int ldc, long long sC,
                  float alpha = 1.f, int beta = 0,
                  const bf16* bias_n = nullptr,
                  const float* scale_n = nullptr, const float* shift_n = nullptr,
                  const bf16* addF = nullptr, int act = 0, bf16* vt = nullptr)
{
  gmfma_x<MF,NF,TC>(st, z, M, N, K, A, lda, sA, 8*sA, Bt, ldb, sB, 8*sB,
                    C, ldc, sC, 8*sC, alpha, beta, bias_n, scale_n, shift_n, addF, act, vt);
}

template<int MF, int NF, typename TC>
static void gmfma_exp(hipStream_t st, int z, int M, int N, int K,
                      const bf16* A, int lda, long long sA, long long sA2,
                      const bf16* Bt, int ldb, long long sB, long long sB2,
                      TC* C, int ldc, long long sC, long long sC2,
                      float alpha,
                      float* srow, long long szl, long long szh, long long sgm)
{
  dim3 g(N/(NF*32), M/(MF*32), z);
  gmfma_k<MF,NF,TC,1><<<g, 256, 0, st>>>(M,N,K,A,lda,sA,sA2,Bt,ldb,sB,sB2,C,ldc,sC,sC2,
                                         alpha,0,nullptr,nullptr,nullptr,nullptr,0,nullptr,
                                         srow,szl,szh,sgm);
}

// ---------- LayerNorm fp32 -> bf16 ----------
__global__ __launch_bounds__(256) void ln_k(const float* __restrict__ X, bf16* __restrict__ Y,
                                            const bf16* __restrict__ w, const bf16* __restrict__ b){
  long long row = blockIdx.x;
  const float* x = X + row*512;
  bf16* y = Y + row*512;
  int tid = threadIdx.x;
  float v0 = x[tid], v1 = x[tid+256];
  float mean = block_reduce<false>(v0+v1) * (1.f/512.f);
  float msq  = block_reduce<false>(v0*v0+v1*v1) * (1.f/512.f);
  float var = msq - mean*mean;
  float rs = rsqrtf(var + 1e-5f);
  y[tid]     = f2b((v0-mean)*rs*b2f(w[tid])     + b2f(b[tid]));
  y[tid+256] = f2b((v1-mean)*rs*b2f(w[tid+256]) + b2f(b[tid+256]));
}

// ---------- fused normalize + 3x3 conv + PV (flash-style tail) ----------
// Sp[b][h][i][j] exp-scores; per block: 8 i-rows, all j. O written directly.
// grid (1, 128, NB). plds: per-head stride 1160 ushorts (16 rows x 72 + 8 pad).
__device__ __forceinline__ int csw(int col){ return col ^ ((col >> 3) & 7); }

__global__ __launch_bounds__(256) void convPV_k(
    const bf16* __restrict__ Sp,
    const bf16* __restrict__ Wr, const bf16* __restrict__ bias,
    const float* __restrict__ Srow,
    const bf16* __restrict__ Vt, bf16* __restrict__ OUTH,
    long long bstride)
{
  __shared__ bf16 tile[10][66][8];
  __shared__ float irow[10][8];
  __shared__ unsigned short plds[8*1160];
  long long b = blockIdx.z;
  int i0 = blockIdx.y*8;
  int tid = threadIdx.x;
  const bf16* src = Sp + b*bstride;

  if (tid < 80){
    int r = tid >> 3, h = tid & 7;
    int gi = i0 + r - 1;
    float iv = 0.f;
    if ((unsigned)gi < 1024u) iv = 1.f / Srow[(b*1024 + gi)*8 + h];
    irow[r][h] = iv;
  }
  // zero plds rows 8..15 (A-frag safety for unused i rows)
  for (int t = tid; t < 8*8*72; t += 256){
    int h = t / 576, rem = t - h*576;
    plds[h*1160 + (8 + rem/72)*72 + (rem - (rem/72)*72)] = 0;
  }

  int lane = tid & 63, wid = tid >> 6;
  int row16 = lane & 15, q = lane >> 4;
  bf16x8 wf0 = *(const bf16x8*)&Wr[row16*96 +  0 + q*8];
  bf16x8 wf1 = *(const bf16x8*)&Wr[row16*96 + 32 + q*8];
  bf16x8 wf2 = *(const bf16x8*)&Wr[row16*96 + 64 + q*8];
  float bv = (row16 < 8) ? b2f(bias[row16]) : 0.f;

  f32x4 zero4 = {0.f,0.f,0.f,0.f};
  f32x4 pacc[2][4];
  #pragma unroll
  for (int hh = 0; hh < 2; ++hh)
    #pragma unroll
    for (int nf = 0; nf < 4; ++nf) pacc[hh][nf] = zero4;
  int h0 = wid*2;

  for (int c = 0; c < 16; ++c){
    int base = c*64;
    __syncthreads();   // tile free (conv done), plds free (PV done), irow ready
    // stage 320 units (10 rows x 4 h-pairs x 8 segs), aligned 16B loads + normalize
    for (int t = tid; t < 320; t += 256){
      int row = t >> 5, rem = t & 31;
      int hp = rem >> 3, seg = rem & 7;
      int gi = i0 + row - 1;
      int g0 = base + seg*8;
      unsigned ov[8];
      if ((unsigned)gi < 1024u){
        const bf16* p0 = src + (long long)(2*hp)*1048576 + (long long)gi*1024 + g0;
        bf16x8 a0 = *(const bf16x8*)p0;
        bf16x8 a1 = *(const bf16x8*)(p0 + 1048576);
        float i0v = irow[row][2*hp];
        float i1v = irow[row][2*hp+1];
        #pragma unroll
        for (int k = 0; k < 8; ++k){
          float e0 = bits2f((unsigned)(unsigned short)a0[k]) * i0v;
          float e1 = bits2f((unsigned)(unsigned short)a1[k]) * i1v;
          ov[k] = (unsigned)f2bits(e0) | ((unsigned)f2bits(e1) << 16);
        }
      } else {
        #pragma unroll
        for (int k = 0; k < 8; ++k) ov[k] = 0u;
      }
      #pragma unroll
      for (int k = 0; k < 8; ++k)
        *(unsigned*)&tile[row][csw(1 + seg*8 + k)][2*hp] = ov[k];
    }
    // halo cols
    if (tid < 40){
      int row = tid >> 2, hp = tid & 3;
      int gi = i0 + row - 1;
      unsigned L = 0u, R = 0u;
      if ((unsigned)gi < 1024u){
        long long rb = (long long)gi*1024;
        int cl = base - 1, cr = base + 64;
        float i0v = irow[row][2*hp];
        float i1v = irow[row][2*hp+1];
        if (cl >= 0){
          float e0 = b2f(src[(long long)(2*hp)*1048576 + rb + cl]) * i0v;
          float e1 = b2f(src[(long long)(2*hp+1)*1048576 + rb + cl]) * i1v;
          L = (unsigned)f2bits(e0) | ((unsigned)f2bits(e1) << 16);
        }
        if (cr < 1024){
          float e0 = b2f(src[(long long)(2*hp)*1048576 + rb + cr]) * i0v;
          float e1 = b2f(src[(long long)(2*hp+1)*1048576 + rb + cr]) * i1v;
          R = (unsigned)f2bits(e0) | ((unsigned)f2bits(e1) << 16);
        }
      }
      *(unsigned*)&tile[row][csw(0)][2*hp] = L;
      *(unsigned*)&tile[row][csw(65)][2*hp] = R;
    }
    __syncthreads();
    // conv: 2 rr x 3 ks x 4 mf MFMA; output -> plds
    #pragma unroll
    for (int rr = 0; rr < 2; ++rr){
      int ii = rr*4 + wid;
      f32x4 acc[4] = {zero4, zero4, zero4, zero4};
      #pragma unroll
      for (int ks = 0; ks < 3; ++ks){
        int tap = ks*4 + q;
        int tcl = tap > 8 ? 0 : tap;
        int di = tcl/3, dj = tcl - di*3;
        bf16x8 wsel = ks==0 ? wf0 : (ks==1 ? wf1 : wf2);
        #pragma unroll
        for (int mf = 0; mf < 4; ++mf){
          bf16x8 af = *(const bf16x8*)&tile[ii+di][csw(mf*16 + row16 + dj)][0];
          acc[mf] = __builtin_amdgcn_mfma_f32_16x16x32_bf16(af, wsel, acc[mf], 0, 0, 0);
        }
      }
      if (row16 < 8){
        unsigned short* pp = &plds[row16*1160 + ii*72];
        #pragma unroll
        for (int mf = 0; mf < 4; ++mf){
          ushort4 o;
          o.x = f2bits(acc[mf][0] + bv);
          o.y = f2bits(acc[mf][1] + bv);
          o.z = f2bits(acc[mf][2] + bv);
          o.w = f2bits(acc[mf][3] + bv);
          *(ushort4*)&pp[mf*16 + q*4] = o;
        }
      }
    }
    __syncthreads();
    // PV: A = plds (M=16 i, K=64 j), Bt = Vt (N=64 d, K=64 j); 2 heads per wave
    #pragma unroll
    for (int hh = 0; hh < 2; ++hh){
      int h = h0 + hh;
      const bf16* vb = Vt + (((long long)b*8 + h) << 16);
      #pragma unroll
      for (int ks = 0; ks < 2; ++ks){
        bf16x8 af = *(const bf16x8*)&plds[h*1160 + row16*72 + ks*32 + q*8];
        #pragma unroll
        for (int nf = 0; nf < 4; ++nf){
          bf16x8 bfv = *(const bf16x8*)&vb[(long long)(nf*16 + row16)*1024 + base + ks*32 + q*8];
          pacc[hh][nf] = __builtin_amdgcn_mfma_f32_16x16x32_bf16(af, bfv, pacc[hh][nf], 0, 0, 0);
        }
      }
    }
  }
  // epilogue: O rows m = q*4+r valid for m<8 (q<2)
  if (q < 2){
    #pragma unroll
    for (int hh = 0; hh < 2; ++hh)
      #pragma unroll
      for (int nf = 0; nf < 4; ++nf)
        #pragma unroll
        for (int r = 0; r < 4; ++r)
          OUTH[((long long)b*1024 + i0 + q*4 + r)*512 + (h0+hh)*64 + nf*16 + row16] =
              f2b(pacc[hh][nf][r]);
  }
}

// ---------- 3x3 conv, 1 ch, normalize-during-staging, bf16 TRANSPOSED out ----------
__global__ __launch_bounds__(256) void conv_spec_k(const float* __restrict__ in, bf16* __restrict__ out,
                                                   const bf16* __restrict__ w, const bf16* __restrict__ bias,
                                                   const float* __restrict__ SSrow){
  __shared__ float ti[66][67];
  __shared__ bf16 toutT[64][65];
  __shared__ float sis[66];
  int b = blockIdx.z;
  int i0 = blockIdx.y*64, j0 = blockIdx.x*64;
  int tid = threadIdx.x;
  const float* ib = in + (long long)b*262144;
  if (tid < 66){
    int gi = i0 + tid - 1;
    float iv = 0.f;
    if ((unsigned)gi < 512u) iv = 1.f / SSrow[b*512 + gi];
    sis[tid] = iv;
  }
  __syncthreads();
  for (int t = tid; t < 66*66; t += 256){
    int r = t / 66, cc = t - r*66;
    int gi = i0 + r - 1, gj = j0 + cc - 1;
    float v = 0.f;
    if ((unsigned)gi < 512u && (unsigned)gj < 512u)
      v = ib[gi*512 + gj] * sis[r];
    ti[r][cc] = v;
  }
  __syncthreads();
  float w9[9], bv = b2f(bias[0]);
  #pragma unroll
  for (int d = 0; d < 9; ++d) w9[d] = b2f(w[d]);
  int ii = tid & 63;
  #pragma unroll
  for (int q = 0; q < 16; ++q){
    int jj = (tid >> 6)*16 + q;
    float acc = bv;
    #pragma unroll
    for (int di = 0; di < 3; ++di)
      #pragma unroll
      for (int dj = 0; dj < 3; ++dj)
        acc += w9[di*3+dj] * ti[ii+di][jj+dj];
    toutT[jj][ii] = f2b(acc);
  }
  __syncthreads();
  #pragma unroll
  for (int q = 0; q < 16; ++q){
    int jj = (tid >> 6)*16 + q;
    out[(long long)b*262144 + (j0+jj)*512 + i0 + (tid & 63)] = toutT[jj][tid & 63];
  }
}

// ---------- depthwise 3x3; Hbuf (b,n,c) bf16 -> T1 (b,n,c) bf16 ----------
__global__ __launch_bounds__(256) void dwconv_k(const bf16* __restrict__ H2, bf16* __restrict__ T1,
                                                const bf16* __restrict__ w, const bf16* __restrict__ bias){
  int p = blockIdx.x*256 + threadIdx.x;
  int cp = p & 255;
  int n = (p >> 8) & 1023;
  int b = p >> 18;
  int c0 = cp*2;
  int wi = n >> 5, hg = n & 31;
  float a0 = b2f(bias[c0]), a1 = b2f(bias[c0+1]);
  #pragma unroll
  for (int di = 0; di < 3; ++di){
    int gw = wi + di - 1;
    if ((unsigned)gw >= 32u) continue;
    #pragma unroll
    for (int dj = 0; dj < 3; ++dj){
      int gh = hg + dj - 1;
      if ((unsigned)gh >= 32u) continue;
      unsigned hv = *(const unsigned*)&H2[((long long)b*1024 + (gw*32+gh))*512 + c0];
      float w0 = b2f(w[c0*9 + di*3 + dj]);
      float w1 = b2f(w[(c0+1)*9 + di*3 + dj]);
      a0 += w0 * bits2f(hv & 0xffffu);
      a1 += w1 * bits2f(hv >> 16);
    }
  }
  bf16 h0 = f2b(a0), h1 = f2b(a1);
  unsigned o = ((unsigned)*(unsigned short*)&h1 << 16) | (unsigned)*(unsigned short*)&h0;
  *(unsigned*)&T1[((long long)b*1024 + n)*512 + c0] = o;
}

// ---------- fold pw bias + BN(eval), all layers ----------
__global__ void bnaff_all_k(const bf16* __restrict__ pwb, const bf16* __restrict__ g,
                            const bf16* __restrict__ bb, const bf16* __restrict__ m,
                            const bf16* __restrict__ v, float* __restrict__ BNAFF){
  int l = blockIdx.x, o = threadIdx.x;
  float s = b2f(g[l*256+o]) * rsqrtf(b2f(v[l*256+o]) + 1e-5f);
  BNAFF[l*512 + o] = s;
  BNAFF[l*512 + 256 + o] = (b2f(pwb[l*256+o]) - b2f(m[l*256+o])) * s + b2f(bb[l*256+o]);
}

// ---------- HbufT[b][c][n] = Hbuf[b][n][c] ----------
__global__ __launch_bounds__(256) void htrans_k(const bf16* __restrict__ Hb, bf16* __restrict__ HT){
  __shared__ bf16 t[64][65];
  int b = blockIdx.z;
  int n0 = blockIdx.x*64, c0 = blockIdx.y*64;
  int lane = threadIdx.x & 63, quad = threadIdx.x >> 6;
  #pragma unroll
  for (int k = 0; k < 16; ++k){
    int r = quad*16 + k;
    t[r][lane] = Hb[((long long)b*1024 + n0 + r)*512 + c0 + lane];
  }
  __syncthreads();
  #pragma unroll
  for (int k = 0; k < 16; ++k){
    int c = quad*16 + k;
    HT[(long long)b*524288 + (long long)(c0+c)*1024 + n0 + lane] = t[lane][c];
  }
}

// ---------- orchestration ----------
extern "C" void kernel_launch(void* const* d_in, const int* in_sizes, int n_in,
                              void* d_out, int out_size, void* d_ws, size_t ws_size,
                              hipStream_t stream)
{
  (void)in_sizes; (void)n_in; (void)out_size;

  const bool big = ws_size >= 207000000ull;
  const long long ATTN_SZ = big ? 33554432LL : 8388608LL;

  // ---- arena ----
  float* X     = (float*)d_ws;
  bf16*  WBsm  = (bf16*)(X + 2097152);
  bf16*  WqkvT = WBsm  + 2139648;
  bf16*  WoutT = WqkvT + 3145728;
  bf16*  WqsT  = WoutT + 1048576;
  bf16*  Hbuf  = WqsT  + 8388608;
  bf16*  HbufT = Hbuf  + 2097152;
  bf16*  QKV   = HbufT + 2097152;
  bf16*  Vt    = QKV   + 6291456;
  bf16*  OUTH  = Vt    + 2097152;
  bf16*  OUT   = OUTH  + 2097152;
  bf16*  ATTN  = OUT   + 2097152;
  bf16*  ATTNC = ATTN  + ATTN_SZ;
  float* BNAFF = (float*)(ATTNC + ATTN_SZ);
  bf16*  WR    = (bf16*)(BNAFF + 2048);
  float* SROW  = (float*)(WR + 6144);
  float* SSROW = SROW + 32768;
  int*   FLAG  = (int*)(SSROW + 2048);

  float* ASPEC   = (float*)OUTH;
  bf16*  ASPECCT = ATTNC;
  bf16*  T1 = ATTN;
  bf16*  T3 = ATTN + 2097152;
  bf16*  T2 = ATTNC + 2097152;
  bf16*  SQK = ATTN;

  // ---- small-weight arena ----
  static const int widx[21] = {1,2,5,6,7,9,10,11,12,13,14,15,16,17,18,19,20,21,22,23,24};
  static const long long wsz[21] = {2048,2048,2048,2304,32,36,4,2048,2048,18432,2048,
                                    524288,1024,1024,1024,1024,1024,524288,2048,1048576,2048};
  WCvt21 wc;
  long long cum = 0;
  bf16* wp[21];
  for (int t = 0; t < 21; ++t){
    wc.src[t] = d_in[widx[t]];
    wc.cum[t] = cum;
    wp[t] = WBsm + cum;
    cum += wsz[t];
  }
  wc.cum[21] = cum;

  bf16 *w_ln1w = wp[0],  *w_ln1b = wp[1],  *w_bout = wp[2],  *w_spw = wp[3];
  bf16 *w_spb  = wp[4],  *w_specw= wp[5],  *w_specb= wp[6],  *w_ln2w= wp[7];
  bf16 *w_ln2b = wp[8],  *w_dww  = wp[9],  *w_dwb  = wp[10], *w_pww = wp[11];
  bf16 *w_pwb  = wp[12], *w_bng  = wp[13], *w_bnb  = wp[14], *w_bnm = wp[15];
  bf16 *w_bnv  = wp[16], *w_c1w  = wp[17], *w_c1b  = wp[18], *w_c2w = wp[19];
  bf16 *w_c2b  = wp[20];

  // ---- setup ----
  detect_k<<<1, 256, 0, stream>>>((const unsigned*)d_in[0], FLAG);
  cvt_x_k<<<8192, 256, 0, stream>>>(d_in[0], X, FLAG);
  cvt_w_k<<<(int)((cum + 255)/256), 256, 0, stream>>>(wc, WBsm, cum, FLAG);
  wtrans_k<<<dim3(8,24,4), 256, 0, stream>>>(d_in[3], WqkvT, 1536, 512, 786432LL, 786432LL, FLAG);
  wtrans_k<<<dim3(8, 8,4), 256, 0, stream>>>(d_in[4], WoutT,  512, 512, 262144LL, 262144LL, FLAG);
  wtrans_k<<<dim3(16,32,4),256, 0, stream>>>(d_in[8], WqsT,  3072,1024, 3145728LL,2097152LL, FLAG);
  bnaff_all_k<<<4, 256, 0, stream>>>(w_pwb, w_bng, w_bnb, w_bnm, w_bnv, BNAFF);
  wprep_k<<<4, 256, 0, stream>>>(w_spw, WR);

  for (int l = 0; l < 4; ++l){
    zero_k<<<136, 256, 0, stream>>>(SROW, 34816);
    // --- spatial attention ---
    ln_k<<<4096, 256, 0, stream>>>(X, Hbuf, w_ln1w + l*512, w_ln1b + l*512);
    gmfma<4,4,bf16>(stream, 1, 4096, 1536, 512,
        Hbuf, 512, 0, WqkvT + (long long)l*786432, 512, 0, QKV, 1536, 0,
        1.f, 0, nullptr, nullptr, nullptr, nullptr, 0, Vt);
    if (big){
      // srow index = h*szl + b*szh + i*sgm = h + b*8192 + i*8
      gmfma_exp<4,4,bf16>(stream, 32, 1024, 1024, 64,
          QKV, 1536, 64, 1572864, QKV + 512, 1536, 64, 1572864,
          ATTN, 1024, 1048576, 8388608, 0.125f,
          SROW, 1, 8192, 8);
      convPV_k<<<dim3(1,128,4), 256, 0, stream>>>(ATTN, WR + l*1536, w_spb + l*8,
                                                  SROW, Vt, OUTH, 8388608LL);
    } else {
      for (int b = 0; b < 4; ++b){
        bf16* qkvb = QKV + (long long)b*1572864;
        gmfma_exp<4,4,bf16>(stream, 8, 1024, 1024, 64,
            qkvb, 1536, 64, 8*64, qkvb + 512, 1536, 64, 8*64,
            ATTN, 1024, 1048576, 8*1048576, 0.125f,
            SROW + b*8192, 1, 0, 8);
        convPV_k<<<dim3(1,128,1), 256, 0, stream>>>(ATTN, WR + l*1536, w_spb + l*8,
                                                    SROW + b*8192, Vt + (long long)b*524288,
                                                    OUTH + (long long)b*524288, 8388608LL);
      }
    }
    gmfma<2,2,bf16>(stream, 1, 4096, 512, 512,
        OUTH, 512, 0, WoutT + (long long)l*262144, 512, 0, OUT, 512, 0,
        1.f, 0, w_bout + l*512);
    // --- spectral attention ---
    htrans_k<<<dim3(16,8,4), 256, 0, stream>>>(Hbuf, HbufT);
    gmfma<4,4,bf16>(stream, 4, 512, 2048, 1024,
        HbufT, 1024, 524288, WqsT + (long long)l*2097152, 1024, 0, SQK, 2048, 1048576);
    gmfma_exp<2,2,float>(stream, 4, 512, 512, 1024,
        SQK, 2048, 1048576, 8*1048576, SQK + 1024, 2048, 1048576, 8*1048576,
        ASPEC, 512, 262144, 8*262144, 0.125f,
        SSROW, 512, 0, 1);
    conv_spec_k<<<dim3(8,8,4), 256, 0, stream>>>(ASPEC, ASPECCT, w_specw + l*9, w_specb + l,
                                                 SSROW);
    gmfma<2,2,float>(stream, 4, 1024, 512, 512,
        OUT, 512, 524288, ASPECCT, 512, 262144, X, 512, 524288, 1.f, 1);
    // --- conv FFN ---
    ln_k<<<4096, 256, 0, stream>>>(X, Hbuf, w_ln2w + l*512, w_ln2b + l*512);
    dwconv_k<<<4096, 256, 0, stream>>>(Hbuf, T1, w_dww + l*4608, w_dwb + l*512);
    gmfma<2,2,bf16>(stream, 4, 1024, 256, 512,
        T1, 512, 524288, w_pww + (long long)l*131072, 512, 0, T2, 256, 262144,
        1.f, 0, nullptr, BNAFF + l*512, BNAFF + l*512 + 256);
    gmfma<2,2,bf16>(stream, 4, 1024, 512, 256,
        T2, 256, 262144, w_c1w + (long long)l*131072, 256, 0, T3, 512, 524288,
        1.f, 0, w_c1b + l*512, nullptr, nullptr, nullptr, 1);
    gmfma<2,2,float>(stream, 4, 1024, 512, 512,
        T3, 512, 524288, w_c2w + (long long)l*262144, 512, 0, X, 512, 524288,
        1.f, 1, w_c2b + l*512, nullptr, nullptr, Hbuf, 1);
  }

  store_out_k<<<8192, 256, 0, stream>>>(X, d_out, FLAG);
}

// Round 17
// 1204.021 us; speedup vs baseline: 1.1499x; 1.1499x over previous
//
#include <hip/hip_runtime.h>
#include <hip/hip_bf16.h>

typedef __hip_bfloat16 bf16;
typedef __attribute__((ext_vector_type(8))) short bf16x8;
typedef __attribute__((ext_vector_type(4))) float f32x4;

// ---------- helpers ----------
__device__ __forceinline__ float b2f(bf16 v){ return __bfloat162float(v); }
__device__ __forceinline__ bf16 f2b(float v){ return __float2bfloat16(v); }
__device__ __forceinline__ float bits2f(unsigned u){ return __uint_as_float(u << 16); }
__device__ __forceinline__ unsigned short f2bits(float v){ bf16 t = __float2bfloat16(v); return *(unsigned short*)&t; }

__device__ __forceinline__ float gelu_f(float x){
  return 0.5f * x * (1.f + erff(x * 0.7071067811865475f));
}

__device__ __forceinline__ void gload_lds(const void* g, void* l){
  __builtin_amdgcn_global_load_lds((const __attribute__((address_space(1))) void*)g,
                                   (__attribute__((address_space(3))) void*)l, 16, 0, 0);
}

template<bool MAX>
__device__ __forceinline__ float block_reduce(float v){
  __shared__ float s[4];
  #pragma unroll
  for (int o = 32; o > 0; o >>= 1){
    float t = __shfl_down(v, o, 64);
    v = MAX ? fmaxf(v, t) : (v + t);
  }
  int lane = threadIdx.x & 63, w = threadIdx.x >> 6;
  __syncthreads();
  if (lane == 0) s[w] = v;
  __syncthreads();
  return MAX ? fmaxf(fmaxf(s[0], s[1]), fmaxf(s[2], s[3]))
             : (s[0] + s[1] + s[2] + s[3]);
}

// ---------- dtype detect + converters ----------
__global__ void detect_k(const unsigned* __restrict__ x, int* __restrict__ flag){
  __shared__ int cnt[256];
  int tid = threadIdx.x;
  int c = 0;
  for (int i = tid; i < 4096; i += 256){
    unsigned h = x[i] & 0xffffu;
    int e = (int)((h >> 7) & 0xff);
    if (h == 0u || (e >= 100 && e <= 133)) c++;
  }
  cnt[tid] = c;
  __syncthreads();
  for (int o = 128; o > 0; o >>= 1){ if (tid < o) cnt[tid] += cnt[tid+o]; __syncthreads(); }
  if (tid == 0) *flag = (cnt[0] < 2048) ? 1 : 0;
}

__global__ __launch_bounds__(256) void cvt_x_k(const void* __restrict__ src,
                                               float* __restrict__ X,
                                               const int* __restrict__ flag){
  int p = blockIdx.x*256 + threadIdx.x;
  X[p] = (*flag) ? ((const float*)src)[p]
                 : __bfloat162float(((const bf16*)src)[p]);
}

struct WCvt21 { const void* src[21]; long long cum[22]; };

__global__ __launch_bounds__(256) void cvt_w_k(WCvt21 a, bf16* __restrict__ WB,
                                               long long total, const int* __restrict__ flag){
  long long i = (long long)blockIdx.x*256 + threadIdx.x;
  if (i >= total) return;
  int t = 0;
  while (a.cum[t+1] <= i) t++;
  long long e = i - a.cum[t];
  WB[i] = (*flag) ? __float2bfloat16(((const float*)a.src[t])[e])
                  : ((const bf16*)a.src[t])[e];
}

// transpose + convert weight: dst[z][c][r] = src[z][r][c], tiles 64x64
__global__ __launch_bounds__(256) void wtrans_k(const void* __restrict__ src, bf16* __restrict__ dst,
                                                int ld_src, int ldd, long long sSrc, long long sDst,
                                                const int* __restrict__ flag){
  __shared__ bf16 t[64][65];
  int z = blockIdx.z;
  int r0 = blockIdx.x*64, c0 = blockIdx.y*64;
  int lane = threadIdx.x & 63, quad = threadIdx.x >> 6;
  const float* sf = (const float*)src;
  const bf16* sb = (const bf16*)src;
  int fl = *flag;
  #pragma unroll
  for (int k = 0; k < 16; ++k){
    int r = quad*16 + k;
    long long idx = z*sSrc + (long long)(r0+r)*ld_src + c0 + lane;
    float v = fl ? sf[idx] : b2f(sb[idx]);
    t[r][lane] = f2b(v);
  }
  __syncthreads();
  #pragma unroll
  for (int k = 0; k < 16; ++k){
    int c = quad*16 + k;
    dst[z*sDst + (long long)(c0+c)*ldd + r0 + lane] = t[lane][c];
  }
}

// conv-attn weight shuffle: Wr[l][16][96]; Wr[l][ho][tap*8+hi] = spw[l][ho][hi][tap], 0-padded
__global__ void wprep_k(const bf16* __restrict__ spw, bf16* __restrict__ Wr){
  int l = blockIdx.x;
  for (int t = threadIdx.x; t < 1536; t += 256){
    int ho = t / 96, k = t - ho*96;
    float v = 0.f;
    if (ho < 8 && k < 72){
      int tap = k >> 3, hi = k & 7;
      v = b2f(spw[l*576 + ho*72 + hi*9 + tap]);
    }
    Wr[l*1536 + t] = f2b(v);
  }
}

__global__ __launch_bounds__(256) void store_out_k(const float* __restrict__ X,
                                                   void* __restrict__ out,
                                                   const int* __restrict__ flag){
  int p = blockIdx.x*256 + threadIdx.x;
  if (*flag) ((float*)out)[p] = X[p];
  else       ((bf16*)out)[p] = f2b(X[p]);
}

__global__ __launch_bounds__(256) void zero_k(float* __restrict__ p, int n){
  int i = blockIdx.x*256 + threadIdx.x;
  if (i < n) p[i] = 0.f;
}

// ---------- MFMA GEMM ----------
// C[z] = epi( alpha * A(MxK,row) x Bt(NxK,row)^T ); z decomposes as (z&7, z>>3)
// EXP=1: C = exp(alpha*acc) (bf16/f32), row sums atomically added to srow.
template<int MF, int NF, typename TC, int EXP>
__global__ __launch_bounds__(256) void gmfma_k(
    int M, int N, int K,
    const bf16* __restrict__ A, int lda, long long sA, long long sA2,
    const bf16* __restrict__ Bt, int ldb, long long sB, long long sB2,
    TC* __restrict__ C, int ldc, long long sC, long long sC2,
    float alpha, int beta,
    const bf16* __restrict__ bias_n,
    const float* __restrict__ scale_n,
    const float* __restrict__ shift_n,
    const bf16* __restrict__ addF,
    int act,
    bf16* __restrict__ vt,
    float* __restrict__ srow, long long szl, long long szh, long long sgm)
{
  constexpr int BM = MF*32, BN = NF*32;
  constexpr int CHA = BM/16, CH = (BM+BN)/16;
  static_assert(CH % 4 == 0, "chunks must divide among 4 waves");
  __shared__ bf16 Asm[BM][32];
  __shared__ bf16 Bsm[BN][32];
  const int tid = threadIdx.x;
  const int lane = tid & 63, wid = tid >> 6;
  const int wm = wid >> 1, wn = wid & 1;
  const int m0 = blockIdx.y*BM, n0 = blockIdx.x*BN;
  const int z = blockIdx.z;
  const long long zl = z & 7, zh = z >> 3;
  const bf16* Ab = A + zl*sA + zh*sA2;
  const bf16* Bb = Bt + zl*sB + zh*sB2;
  TC* Cb = C + zl*sC + zh*sC2;
  const bf16* Fb = addF ? addF + zl*sC + zh*sC2 : nullptr;

  f32x4 acc[MF][NF];
  f32x4 zero = {0.f, 0.f, 0.f, 0.f};
  #pragma unroll
  for (int m = 0; m < MF; ++m)
    #pragma unroll
    for (int n = 0; n < NF; ++n) acc[m][n] = zero;

  const int rchunk = lane >> 2;
  const int kchunk = (lane & 3) * 8;
  const int row16 = lane & 15, kq = (lane >> 4) * 8;

  for (int k0 = 0; k0 < K; k0 += 32){
    #pragma unroll
    for (int cc = 0; cc < CH/4; ++cc){
      int c = wid + cc*4;
      if (c < CHA){
        int row = c*16 + rchunk;
        gload_lds(Ab + (long long)(m0+row)*lda + k0 + kchunk, &Asm[c*16][0]);
      } else {
        int row = (c-CHA)*16 + rchunk;
        gload_lds(Bb + (long long)(n0+row)*ldb + k0 + kchunk, &Bsm[(c-CHA)*16][0]);
      }
    }
    __syncthreads();
    bf16x8 af[MF], bfr[NF];
    #pragma unroll
    for (int m = 0; m < MF; ++m)
      af[m] = *(const bf16x8*)&Asm[wm*(MF*16) + m*16 + row16][kq];
    #pragma unroll
    for (int n = 0; n < NF; ++n)
      bfr[n] = *(const bf16x8*)&Bsm[wn*(NF*16) + n*16 + row16][kq];
    #pragma unroll
    for (int m = 0; m < MF; ++m)
      #pragma unroll
      for (int n = 0; n < NF; ++n)
        acc[m][n] = __builtin_amdgcn_mfma_f32_16x16x32_bf16(af[m], bfr[n], acc[m][n], 0, 0, 0);
    __syncthreads();
  }

  if constexpr (EXP){
    // e = exp(alpha*acc); store; butterfly row-sum over lane&15; atomicAdd per row.
    #pragma unroll
    for (int m = 0; m < MF; ++m){
      int gmb = m0 + wm*(MF*16) + m*16 + (lane >> 4)*4;
      float rowsum[4] = {0.f, 0.f, 0.f, 0.f};
      #pragma unroll
      for (int n = 0; n < NF; ++n){
        int gn = n0 + wn*(NF*16) + n*16 + row16;
        #pragma unroll
        for (int r = 0; r < 4; ++r){
          float e = __expf(acc[m][n][r] * alpha);
          long long idx = (long long)(gmb + r)*ldc + gn;
          if constexpr (__is_same(TC, float)) Cb[idx] = e; else Cb[idx] = f2b(e);
          rowsum[r] += e;
        }
      }
      #pragma unroll
      for (int r = 0; r < 4; ++r){
        float s = rowsum[r];
        #pragma unroll
        for (int o = 1; o < 16; o <<= 1) s += __shfl_xor(s, o, 64);
        if ((lane & 15) == 0)
          atomicAdd(&srow[zl*szl + zh*szh + (long long)(gmb + r)*sgm], s);
      }
    }
    return;
  }

  #pragma unroll
  for (int m = 0; m < MF; ++m){
    #pragma unroll
    for (int n = 0; n < NF; ++n){
      int gn = n0 + wn*(NF*16) + n*16 + row16;
      float bn_ = bias_n ? b2f(bias_n[gn]) : 0.f;
      float sc = scale_n ? scale_n[gn] : 1.f;
      float sh = shift_n ? shift_n[gn] : 0.f;
      int gmb = m0 + wm*(MF*16) + m*16 + (lane >> 4)*4;
      float vals[4];
      #pragma unroll
      for (int r = 0; r < 4; ++r){
        int gm = gmb + r;
        float v = acc[m][n][r] * alpha + bn_;
        v = v * sc + sh;
        if (act) v = gelu_f(v);
        long long idx = (long long)gm*ldc + gn;
        if (Fb) v += b2f(Fb[idx]);
        if (beta){
          float old;
          if constexpr (__is_same(TC, float)) old = Cb[idx]; else old = b2f(Cb[idx]);
          v += old;
        }
        if constexpr (__is_same(TC, float)) Cb[idx] = v; else Cb[idx] = f2b(v);
        vals[r] = v;
      }
      if (vt && gn >= 1024){
        int h = (gn - 1024) >> 6, d = (gn - 1024) & 63;
        int bb = gmb >> 10, nn = gmb & 1023;
        ushort4 o;
        o.x = f2bits(vals[0]); o.y = f2bits(vals[1]);
        o.z = f2bits(vals[2]); o.w = f2bits(vals[3]);
        *(ushort4*)&vt[(((long long)bb*8 + h)*64 + d)*1024 + nn] = o;
      }
    }
  }
}

template<int MF, int NF, typename TC>
static void gmfma_x(hipStream_t st, int z, int M, int N, int K,
                    const bf16* A, int lda, long long sA, long long sA2,
                    const bf16* Bt, int ldb, long long sB, long long sB2,
                    TC* C, int ldc, long long sC, long long sC2,
                    float alpha = 1.f, int beta = 0,
                    const bf16* bias_n = nullptr,
                    const float* scale_n = nullptr, const float* shift_n = nullptr,
                    const bf16* addF = nullptr, int act = 0, bf16* vt = nullptr)
{
  dim3 g(N/(NF*32), M/(MF*32), z);
  gmfma_k<MF,NF,TC,0><<<g, 256, 0, st>>>(M,N,K,A,lda,sA,sA2,Bt,ldb,sB,sB2,C,ldc,sC,sC2,
                                         alpha,beta,bias_n,scale_n,shift_n,addF,act,vt,
                                         nullptr,0,0,0);
}

template<int MF, int NF, typename TC>
static void gmfma(hipStream_t st, int z, int M, int N, int K,
                  const bf16* A, int lda, long long sA,
                  const bf16* Bt, int ldb, long long sB,
                  TC* C, int ldc, long long sC,
                  float alpha = 1.f, int beta = 0,
                  const bf16* bias_n = nullptr,
                  const float* scale_n = nullptr, const float* shift_n = nullptr,
                  const bf16* addF = nullptr, int act = 0, bf16* vt = nullptr)
{
  gmfma_x<MF,NF,TC>(st, z, M, N, K, A, lda, sA, 8*sA, Bt, ldb, sB, 8*sB,
                    C, ldc, sC, 8*sC, alpha, beta, bias_n, scale_n, shift_n, addF, act, vt);
}

template<int MF, int NF, typename TC>
static void gmfma_exp(hipStream_t st, int z, int M, int N, int K,
                      const bf16* A, int lda, long long sA, long long sA2,
                      const bf16* Bt, int ldb, long long sB, long long sB2,
                      TC* C, int ldc, long long sC, long long sC2,
                      float alpha,
                      float* srow, long long szl, long long szh, long long sgm)
{
  dim3 g(N/(NF*32), M/(MF*32), z);
  gmfma_k<MF,NF,TC,1><<<g, 256, 0, st>>>(M,N,K,A,lda,sA,sA2,Bt,ldb,sB,sB2,C,ldc,sC,sC2,
                                         alpha,0,nullptr,nullptr,nullptr,nullptr,0,nullptr,
                                         srow,szl,szh,sgm);
}

// ---------- LayerNorm fp32 -> bf16 ----------
__global__ __launch_bounds__(256) void ln_k(const float* __restrict__ X, bf16* __restrict__ Y,
                                            const bf16* __restrict__ w, const bf16* __restrict__ b){
  long long row = blockIdx.x;
  const float* x = X + row*512;
  bf16* y = Y + row*512;
  int tid = threadIdx.x;
  float v0 = x[tid], v1 = x[tid+256];
  float mean = block_reduce<false>(v0+v1) * (1.f/512.f);
  float msq  = block_reduce<false>(v0*v0+v1*v1) * (1.f/512.f);
  float var = msq - mean*mean;
  float rs = rsqrtf(var + 1e-5f);
  y[tid]     = f2b((v0-mean)*rs*b2f(w[tid])     + b2f(b[tid]));
  y[tid+256] = f2b((v1-mean)*rs*b2f(w[tid+256]) + b2f(b[tid+256]));
}

// ---------- fused normalize + 3x3 MFMA conv (input = exp scores, SROW = row sums) ----------
// grid (2 j-halves, 128 i-tiles, NB); 8-row tiles; 8 chunks of 64 cols.
__device__ __forceinline__ int csw(int col){ return col ^ ((col >> 3) & 7); }

__global__ __launch_bounds__(256) void convNorm_k(
    const bf16* __restrict__ Sp, bf16* __restrict__ Pout,
    const bf16* __restrict__ Wr, const bf16* __restrict__ bias,
    const float* __restrict__ Srow,
    long long bstride)
{
  __shared__ bf16 tile[10][66][8];
  __shared__ float irow[10][8];
  long long b = blockIdx.z;
  int i0 = blockIdx.y*8;
  int jh0 = blockIdx.x*512;
  int tid = threadIdx.x;
  const bf16* src = Sp + b*bstride;

  if (tid < 80){
    int r = tid >> 3, h = tid & 7;
    int gi = i0 + r - 1;
    float iv = 0.f;
    if ((unsigned)gi < 1024u) iv = 1.f / Srow[(b*1024 + gi)*8 + h];
    irow[r][h] = iv;
  }

  int lane = tid & 63, wid = tid >> 6;
  int row16 = lane & 15, q = lane >> 4;
  bf16x8 wf0 = *(const bf16x8*)&Wr[row16*96 +  0 + q*8];
  bf16x8 wf1 = *(const bf16x8*)&Wr[row16*96 + 32 + q*8];
  bf16x8 wf2 = *(const bf16x8*)&Wr[row16*96 + 64 + q*8];
  float bv = (row16 < 8) ? b2f(bias[row16]) : 0.f;

  for (int c = 0; c < 8; ++c){
    int base = jh0 + c*64;
    __syncthreads();
    for (int t = tid; t < 320; t += 256){
      int row = t >> 5, rem = t & 31;
      int hp = rem >> 3, seg = rem & 7;
      int gi = i0 + row - 1;
      int g0 = base + seg*8;
      unsigned ov[8];
      if ((unsigned)gi < 1024u){
        const bf16* p0 = src + (long long)(2*hp)*1048576 + (long long)gi*1024 + g0;
        bf16x8 a0 = *(const bf16x8*)p0;
        bf16x8 a1 = *(const bf16x8*)(p0 + 1048576);
        float i0v = irow[row][2*hp];
        float i1v = irow[row][2*hp+1];
        #pragma unroll
        for (int k = 0; k < 8; ++k){
          float e0 = bits2f((unsigned)(unsigned short)a0[k]) * i0v;
          float e1 = bits2f((unsigned)(unsigned short)a1[k]) * i1v;
          ov[k] = (unsigned)f2bits(e0) | ((unsigned)f2bits(e1) << 16);
        }
      } else {
        #pragma unroll
        for (int k = 0; k < 8; ++k) ov[k] = 0u;
      }
      #pragma unroll
      for (int k = 0; k < 8; ++k)
        *(unsigned*)&tile[row][csw(1 + seg*8 + k)][2*hp] = ov[k];
    }
    if (tid < 40){
      int row = tid >> 2, hp = tid & 3;
      int gi = i0 + row - 1;
      unsigned L = 0u, R = 0u;
      if ((unsigned)gi < 1024u){
        long long rb = (long long)gi*1024;
        int cl = base - 1, cr = base + 64;
        float i0v = irow[row][2*hp];
        float i1v = irow[row][2*hp+1];
        if (cl >= 0){
          float e0 = b2f(src[(long long)(2*hp)*1048576 + rb + cl]) * i0v;
          float e1 = b2f(src[(long long)(2*hp+1)*1048576 + rb + cl]) * i1v;
          L = (unsigned)f2bits(e0) | ((unsigned)f2bits(e1) << 16);
        }
        if (cr < 1024){
          float e0 = b2f(src[(long long)(2*hp)*1048576 + rb + cr]) * i0v;
          float e1 = b2f(src[(long long)(2*hp+1)*1048576 + rb + cr]) * i1v;
          R = (unsigned)f2bits(e0) | ((unsigned)f2bits(e1) << 16);
        }
      }
      *(unsigned*)&tile[row][csw(0)][2*hp] = L;
      *(unsigned*)&tile[row][csw(65)][2*hp] = R;
    }
    __syncthreads();
    #pragma unroll
    for (int rr = 0; rr < 2; ++rr){
      int ii = rr*4 + wid;
      f32x4 zero = {0.f,0.f,0.f,0.f};
      f32x4 acc[4] = {zero,zero,zero,zero};
      #pragma unroll
      for (int ks = 0; ks < 3; ++ks){
        int tap = ks*4 + q;
        int tcl = tap > 8 ? 0 : tap;
        int di = tcl/3, dj = tcl - di*3;
        bf16x8 wsel = ks==0 ? wf0 : (ks==1 ? wf1 : wf2);
        #pragma unroll
        for (int mf = 0; mf < 4; ++mf){
          bf16x8 af = *(const bf16x8*)&tile[ii+di][csw(mf*16 + row16 + dj)][0];
          acc[mf] = __builtin_amdgcn_mfma_f32_16x16x32_bf16(af, wsel, acc[mf], 0, 0, 0);
        }
      }
      if (row16 < 8){
        bf16* dst = Pout + b*bstride + (long long)row16*1048576 + (long long)(i0+ii)*1024;
        #pragma unroll
        for (int mf = 0; mf < 4; ++mf){
          int j = base + mf*16 + q*4;
          ushort4 o;
          o.x = f2bits(acc[mf][0] + bv);
          o.y = f2bits(acc[mf][1] + bv);
          o.z = f2bits(acc[mf][2] + bv);
          o.w = f2bits(acc[mf][3] + bv);
          *(ushort4*)&dst[j] = o;
        }
      }
    }
  }
}

// ---------- 3x3 conv, 1 ch, normalize-during-staging, bf16 TRANSPOSED out ----------
__global__ __launch_bounds__(256) void conv_spec_k(const float* __restrict__ in, bf16* __restrict__ out,
                                                   const bf16* __restrict__ w, const bf16* __restrict__ bias,
                                                   const float* __restrict__ SSrow){
  __shared__ float ti[66][67];
  __shared__ bf16 toutT[64][65];
  __shared__ float sis[66];
  int b = blockIdx.z;
  int i0 = blockIdx.y*64, j0 = blockIdx.x*64;
  int tid = threadIdx.x;
  const float* ib = in + (long long)b*262144;
  if (tid < 66){
    int gi = i0 + tid - 1;
    float iv = 0.f;
    if ((unsigned)gi < 512u) iv = 1.f / SSrow[b*512 + gi];
    sis[tid] = iv;
  }
  __syncthreads();
  for (int t = tid; t < 66*66; t += 256){
    int r = t / 66, cc = t - r*66;
    int gi = i0 + r - 1, gj = j0 + cc - 1;
    float v = 0.f;
    if ((unsigned)gi < 512u && (unsigned)gj < 512u)
      v = ib[gi*512 + gj] * sis[r];
    ti[r][cc] = v;
  }
  __syncthreads();
  float w9[9], bv = b2f(bias[0]);
  #pragma unroll
  for (int d = 0; d < 9; ++d) w9[d] = b2f(w[d]);
  int ii = tid & 63;
  #pragma unroll
  for (int q = 0; q < 16; ++q){
    int jj = (tid >> 6)*16 + q;
    float acc = bv;
    #pragma unroll
    for (int di = 0; di < 3; ++di)
      #pragma unroll
      for (int dj = 0; dj < 3; ++dj)
        acc += w9[di*3+dj] * ti[ii+di][jj+dj];
    toutT[jj][ii] = f2b(acc);
  }
  __syncthreads();
  #pragma unroll
  for (int q = 0; q < 16; ++q){
    int jj = (tid >> 6)*16 + q;
    out[(long long)b*262144 + (j0+jj)*512 + i0 + (tid & 63)] = toutT[jj][tid & 63];
  }
}

// ---------- depthwise 3x3; Hbuf (b,n,c) bf16 -> T1 (b,n,c) bf16 ----------
__global__ __launch_bounds__(256) void dwconv_k(const bf16* __restrict__ H2, bf16* __restrict__ T1,
                                                const bf16* __restrict__ w, const bf16* __restrict__ bias){
  int p = blockIdx.x*256 + threadIdx.x;
  int cp = p & 255;
  int n = (p >> 8) & 1023;
  int b = p >> 18;
  int c0 = cp*2;
  int wi = n >> 5, hg = n & 31;
  float a0 = b2f(bias[c0]), a1 = b2f(bias[c0+1]);
  #pragma unroll
  for (int di = 0; di < 3; ++di){
    int gw = wi + di - 1;
    if ((unsigned)gw >= 32u) continue;
    #pragma unroll
    for (int dj = 0; dj < 3; ++dj){
      int gh = hg + dj - 1;
      if ((unsigned)gh >= 32u) continue;
      unsigned hv = *(const unsigned*)&H2[((long long)b*1024 + (gw*32+gh))*512 + c0];
      float w0 = b2f(w[c0*9 + di*3 + dj]);
      float w1 = b2f(w[(c0+1)*9 + di*3 + dj]);
      a0 += w0 * bits2f(hv & 0xffffu);
      a1 += w1 * bits2f(hv >> 16);
    }
  }
  bf16 h0 = f2b(a0), h1 = f2b(a1);
  unsigned o = ((unsigned)*(unsigned short*)&h1 << 16) | (unsigned)*(unsigned short*)&h0;
  *(unsigned*)&T1[((long long)b*1024 + n)*512 + c0] = o;
}

// ---------- fold pw bias + BN(eval), all layers ----------
__global__ void bnaff_all_k(const bf16* __restrict__ pwb, const bf16* __restrict__ g,
                            const bf16* __restrict__ bb, const bf16* __restrict__ m,
                            const bf16* __restrict__ v, float* __restrict__ BNAFF){
  int l = blockIdx.x, o = threadIdx.x;
  float s = b2f(g[l*256+o]) * rsqrtf(b2f(v[l*256+o]) + 1e-5f);
  BNAFF[l*512 + o] = s;
  BNAFF[l*512 + 256 + o] = (b2f(pwb[l*256+o]) - b2f(m[l*256+o])) * s + b2f(bb[l*256+o]);
}

// ---------- HbufT[b][c][n] = Hbuf[b][n][c] ----------
__global__ __launch_bounds__(256) void htrans_k(const bf16* __restrict__ Hb, bf16* __restrict__ HT){
  __shared__ bf16 t[64][65];
  int b = blockIdx.z;
  int n0 = blockIdx.x*64, c0 = blockIdx.y*64;
  int lane = threadIdx.x & 63, quad = threadIdx.x >> 6;
  #pragma unroll
  for (int k = 0; k < 16; ++k){
    int r = quad*16 + k;
    t[r][lane] = Hb[((long long)b*1024 + n0 + r)*512 + c0 + lane];
  }
  __syncthreads();
  #pragma unroll
  for (int k = 0; k < 16; ++k){
    int c = quad*16 + k;
    HT[(long long)b*524288 + (long long)(c0+c)*1024 + n0 + lane] = t[lane][c];
  }
}

// ---------- orchestration ----------
extern "C" void kernel_launch(void* const* d_in, const int* in_sizes, int n_in,
                              void* d_out, int out_size, void* d_ws, size_t ws_size,
                              hipStream_t stream)
{
  (void)in_sizes; (void)n_in; (void)out_size;

  const bool big = ws_size >= 207000000ull;
  const long long ATTN_SZ = big ? 33554432LL : 8388608LL;

  // ---- arena ----
  float* X     = (float*)d_ws;
  bf16*  WBsm  = (bf16*)(X + 2097152);
  bf16*  WqkvT = WBsm  + 2139648;
  bf16*  WoutT = WqkvT + 3145728;
  bf16*  WqsT  = WoutT + 1048576;
  bf16*  Hbuf  = WqsT  + 8388608;
  bf16*  HbufT = Hbuf  + 2097152;
  bf16*  QKV   = HbufT + 2097152;
  bf16*  Vt    = QKV   + 6291456;
  bf16*  OUTH  = Vt    + 2097152;
  bf16*  OUT   = OUTH  + 2097152;
  bf16*  ATTN  = OUT   + 2097152;
  bf16*  ATTNC = ATTN  + ATTN_SZ;
  float* BNAFF = (float*)(ATTNC + ATTN_SZ);
  bf16*  WR    = (bf16*)(BNAFF + 2048);
  float* SROW  = (float*)(WR + 6144);
  float* SSROW = SROW + 32768;
  int*   FLAG  = (int*)(SSROW + 2048);

  float* ASPEC   = (float*)OUTH;
  bf16*  ASPECCT = ATTNC;
  bf16*  T1 = ATTN;
  bf16*  T3 = ATTN + 2097152;
  bf16*  T2 = ATTNC + 2097152;
  bf16*  SQK = ATTN;

  // ---- small-weight arena ----
  static const int widx[21] = {1,2,5,6,7,9,10,11,12,13,14,15,16,17,18,19,20,21,22,23,24};
  static const long long wsz[21] = {2048,2048,2048,2304,32,36,4,2048,2048,18432,2048,
                                    524288,1024,1024,1024,1024,1024,524288,2048,1048576,2048};
  WCvt21 wc;
  long long cum = 0;
  bf16* wp[21];
  for (int t = 0; t < 21; ++t){
    wc.src[t] = d_in[widx[t]];
    wc.cum[t] = cum;
    wp[t] = WBsm + cum;
    cum += wsz[t];
  }
  wc.cum[21] = cum;

  bf16 *w_ln1w = wp[0],  *w_ln1b = wp[1],  *w_bout = wp[2],  *w_spw = wp[3];
  bf16 *w_spb  = wp[4],  *w_specw= wp[5],  *w_specb= wp[6],  *w_ln2w= wp[7];
  bf16 *w_ln2b = wp[8],  *w_dww  = wp[9],  *w_dwb  = wp[10], *w_pww = wp[11];
  bf16 *w_pwb  = wp[12], *w_bng  = wp[13], *w_bnb  = wp[14], *w_bnm = wp[15];
  bf16 *w_bnv  = wp[16], *w_c1w  = wp[17], *w_c1b  = wp[18], *w_c2w = wp[19];
  bf16 *w_c2b  = wp[20];

  // ---- setup ----
  detect_k<<<1, 256, 0, stream>>>((const unsigned*)d_in[0], FLAG);
  cvt_x_k<<<8192, 256, 0, stream>>>(d_in[0], X, FLAG);
  cvt_w_k<<<(int)((cum + 255)/256), 256, 0, stream>>>(wc, WBsm, cum, FLAG);
  wtrans_k<<<dim3(8,24,4), 256, 0, stream>>>(d_in[3], WqkvT, 1536, 512, 786432LL, 786432LL, FLAG);
  wtrans_k<<<dim3(8, 8,4), 256, 0, stream>>>(d_in[4], WoutT,  512, 512, 262144LL, 262144LL, FLAG);
  wtrans_k<<<dim3(16,32,4),256, 0, stream>>>(d_in[8], WqsT,  3072,1024, 3145728LL,2097152LL, FLAG);
  bnaff_all_k<<<4, 256, 0, stream>>>(w_pwb, w_bng, w_bnb, w_bnm, w_bnv, BNAFF);
  wprep_k<<<4, 256, 0, stream>>>(w_spw, WR);

  for (int l = 0; l < 4; ++l){
    zero_k<<<136, 256, 0, stream>>>(SROW, 34816);
    // --- spatial attention ---
    ln_k<<<4096, 256, 0, stream>>>(X, Hbuf, w_ln1w + l*512, w_ln1b + l*512);
    gmfma<4,4,bf16>(stream, 1, 4096, 1536, 512,
        Hbuf, 512, 0, WqkvT + (long long)l*786432, 512, 0, QKV, 1536, 0,
        1.f, 0, nullptr, nullptr, nullptr, nullptr, 0, Vt);
    if (big){
      // srow index = h*szl + b*szh + i*sgm = h + b*8192 + i*8
      gmfma_exp<4,4,bf16>(stream, 32, 1024, 1024, 64,
          QKV, 1536, 64, 1572864, QKV + 512, 1536, 64, 1572864,
          ATTN, 1024, 1048576, 8388608, 0.125f,
          SROW, 1, 8192, 8);
      convNorm_k<<<dim3(2,128,4), 256, 0, stream>>>(ATTN, ATTNC, WR + l*1536, w_spb + l*8,
                                                    SROW, 8388608LL);
      gmfma_x<2,2,bf16>(stream, 32, 1024, 64, 1024,
          ATTNC, 1024, 1048576, 8388608, Vt, 1024, 65536, 524288,
          OUTH, 512, 64, 524288);
    } else {
      for (int b = 0; b < 4; ++b){
        bf16* qkvb = QKV + (long long)b*1572864;
        gmfma_exp<4,4,bf16>(stream, 8, 1024, 1024, 64,
            qkvb, 1536, 64, 8*64, qkvb + 512, 1536, 64, 8*64,
            ATTN, 1024, 1048576, 8*1048576, 0.125f,
            SROW + b*8192, 1, 0, 8);
        convNorm_k<<<dim3(2,128,1), 256, 0, stream>>>(ATTN, ATTNC, WR + l*1536, w_spb + l*8,
                                                      SROW + b*8192, 8388608LL);
        gmfma<2,2,bf16>(stream, 8, 1024, 64, 1024,
            ATTNC, 1024, 1048576, Vt + (long long)b*524288, 1024, 65536,
            OUTH + (long long)b*524288, 512, 64);
      }
    }
    gmfma<2,2,bf16>(stream, 1, 4096, 512, 512,
        OUTH, 512, 0, WoutT + (long long)l*262144, 512, 0, OUT, 512, 0,
        1.f, 0, w_bout + l*512);
    // --- spectral attention ---
    htrans_k<<<dim3(16,8,4), 256, 0, stream>>>(Hbuf, HbufT);
    gmfma<4,4,bf16>(stream, 4, 512, 2048, 1024,
        HbufT, 1024, 524288, WqsT + (long long)l*2097152, 1024, 0, SQK, 2048, 1048576);
    gmfma_exp<2,2,float>(stream, 4, 512, 512, 1024,
        SQK, 2048, 1048576, 8*1048576, SQK + 1024, 2048, 1048576, 8*1048576,
        ASPEC, 512, 262144, 8*262144, 0.125f,
        SSROW, 512, 0, 1);
    conv_spec_k<<<dim3(8,8,4), 256, 0, stream>>>(ASPEC, ASPECCT, w_specw + l*9, w_specb + l,
                                                 SSROW);
    gmfma<2,2,float>(stream, 4, 1024, 512, 512,
        OUT, 512, 524288, ASPECCT, 512, 262144, X, 512, 524288, 1.f, 1);
    // --- conv FFN ---
    ln_k<<<4096, 256, 0, stream>>>(X, Hbuf, w_ln2w + l*512, w_ln2b + l*512);
    dwconv_k<<<4096, 256, 0, stream>>>(Hbuf, T1, w_dww + l*4608, w_dwb + l*512);
    gmfma<2,2,bf16>(stream, 4, 1024, 256, 512,
        T1, 512, 524288, w_pww + (long long)l*131072, 512, 0, T2, 256, 262144,
        1.f, 0, nullptr, BNAFF + l*512, BNAFF + l*512 + 256);
    gmfma<2,2,bf16>(stream, 4, 1024, 512, 256,
        T2, 256, 262144, w_c1w + (long long)l*131072, 256, 0, T3, 512, 524288,
        1.f, 0, w_c1b + l*512, nullptr, nullptr, nullptr, 1);
    gmfma<2,2,float>(stream, 4, 1024, 512, 512,
        T3, 512, 524288, w_c2w + (long long)l*262144, 512, 0, X, 512, 524288,
        1.f, 1, w_c2b + l*512, nullptr, nullptr, Hbuf, 1);
  }

  store_out_k<<<8192, 256, 0, stream>>>(X, d_out, FLAG);
}

// Round 18
// 1145.012 us; speedup vs baseline: 1.2092x; 1.0515x over previous
//
#include <hip/hip_runtime.h>
#include <hip/hip_bf16.h>

typedef __hip_bfloat16 bf16;
typedef __attribute__((ext_vector_type(8))) short bf16x8;
typedef __attribute__((ext_vector_type(4))) float f32x4;

// ---------- helpers ----------
__device__ __forceinline__ float b2f(bf16 v){ return __bfloat162float(v); }
__device__ __forceinline__ bf16 f2b(float v){ return __float2bfloat16(v); }
__device__ __forceinline__ float bits2f(unsigned u){ return __uint_as_float(u << 16); }
__device__ __forceinline__ unsigned short f2bits(float v){ bf16 t = __float2bfloat16(v); return *(unsigned short*)&t; }

__device__ __forceinline__ float gelu_f(float x){
  return 0.5f * x * (1.f + erff(x * 0.7071067811865475f));
}

__device__ __forceinline__ void gload_lds(const void* g, void* l){
  __builtin_amdgcn_global_load_lds((const __attribute__((address_space(1))) void*)g,
                                   (__attribute__((address_space(3))) void*)l, 16, 0, 0);
}

template<bool MAX>
__device__ __forceinline__ float block_reduce(float v){
  __shared__ float s[4];
  #pragma unroll
  for (int o = 32; o > 0; o >>= 1){
    float t = __shfl_down(v, o, 64);
    v = MAX ? fmaxf(v, t) : (v + t);
  }
  int lane = threadIdx.x & 63, w = threadIdx.x >> 6;
  __syncthreads();
  if (lane == 0) s[w] = v;
  __syncthreads();
  return MAX ? fmaxf(fmaxf(s[0], s[1]), fmaxf(s[2], s[3]))
             : (s[0] + s[1] + s[2] + s[3]);
}

// ---------- dtype detect + converters ----------
__global__ void detect_k(const unsigned* __restrict__ x, int* __restrict__ flag){
  __shared__ int cnt[256];
  int tid = threadIdx.x;
  int c = 0;
  for (int i = tid; i < 4096; i += 256){
    unsigned h = x[i] & 0xffffu;
    int e = (int)((h >> 7) & 0xff);
    if (h == 0u || (e >= 100 && e <= 133)) c++;
  }
  cnt[tid] = c;
  __syncthreads();
  for (int o = 128; o > 0; o >>= 1){ if (tid < o) cnt[tid] += cnt[tid+o]; __syncthreads(); }
  if (tid == 0) *flag = (cnt[0] < 2048) ? 1 : 0;
}

__global__ __launch_bounds__(256) void cvt_x_k(const void* __restrict__ src,
                                               float* __restrict__ X,
                                               const int* __restrict__ flag){
  int p = blockIdx.x*256 + threadIdx.x;
  X[p] = (*flag) ? ((const float*)src)[p]
                 : __bfloat162float(((const bf16*)src)[p]);
}

struct WCvt21 { const void* src[21]; long long cum[22]; };

__global__ __launch_bounds__(256) void cvt_w_k(WCvt21 a, bf16* __restrict__ WB,
                                               long long total, const int* __restrict__ flag){
  long long i = (long long)blockIdx.x*256 + threadIdx.x;
  if (i >= total) return;
  int t = 0;
  while (a.cum[t+1] <= i) t++;
  long long e = i - a.cum[t];
  WB[i] = (*flag) ? __float2bfloat16(((const float*)a.src[t])[e])
                  : ((const bf16*)a.src[t])[e];
}

// transpose + convert weight: dst[z][c][r] = src[z][r][c], tiles 64x64
__global__ __launch_bounds__(256) void wtrans_k(const void* __restrict__ src, bf16* __restrict__ dst,
                                                int ld_src, int ldd, long long sSrc, long long sDst,
                                                const int* __restrict__ flag){
  __shared__ bf16 t[64][65];
  int z = blockIdx.z;
  int r0 = blockIdx.x*64, c0 = blockIdx.y*64;
  int lane = threadIdx.x & 63, quad = threadIdx.x >> 6;
  const float* sf = (const float*)src;
  const bf16* sb = (const bf16*)src;
  int fl = *flag;
  #pragma unroll
  for (int k = 0; k < 16; ++k){
    int r = quad*16 + k;
    long long idx = z*sSrc + (long long)(r0+r)*ld_src + c0 + lane;
    float v = fl ? sf[idx] : b2f(sb[idx]);
    t[r][lane] = f2b(v);
  }
  __syncthreads();
  #pragma unroll
  for (int k = 0; k < 16; ++k){
    int c = quad*16 + k;
    dst[z*sDst + (long long)(c0+c)*ldd + r0 + lane] = t[lane][c];
  }
}

// conv-attn weight shuffle: Wr[l][16][96]; Wr[l][ho][tap*8+hi] = spw[l][ho][hi][tap], 0-padded
__global__ void wprep_k(const bf16* __restrict__ spw, bf16* __restrict__ Wr){
  int l = blockIdx.x;
  for (int t = threadIdx.x; t < 1536; t += 256){
    int ho = t / 96, k = t - ho*96;
    float v = 0.f;
    if (ho < 8 && k < 72){
      int tap = k >> 3, hi = k & 7;
      v = b2f(spw[l*576 + ho*72 + hi*9 + tap]);
    }
    Wr[l*1536 + t] = f2b(v);
  }
}

__global__ __launch_bounds__(256) void store_out_k(const float* __restrict__ X,
                                                   void* __restrict__ out,
                                                   const int* __restrict__ flag){
  int p = blockIdx.x*256 + threadIdx.x;
  if (*flag) ((float*)out)[p] = X[p];
  else       ((bf16*)out)[p] = f2b(X[p]);
}

__global__ __launch_bounds__(256) void zero_k(float* __restrict__ p, int n){
  int i = blockIdx.x*256 + threadIdx.x;
  if (i < n) p[i] = 0.f;
}

// ---------- MFMA GEMM ----------
// C[z] = epi( alpha * A(MxK,row) x Bt(NxK,row)^T ); z decomposes as (z&7, z>>3)
// EXP=1: C = exp(alpha*acc) (bf16/f32), row sums atomically added to srow.
template<int MF, int NF, typename TC, int EXP>
__global__ __launch_bounds__(256) void gmfma_k(
    int M, int N, int K,
    const bf16* __restrict__ A, int lda, long long sA, long long sA2,
    const bf16* __restrict__ Bt, int ldb, long long sB, long long sB2,
    TC* __restrict__ C, int ldc, long long sC, long long sC2,
    float alpha, int beta,
    const bf16* __restrict__ bias_n,
    const float* __restrict__ scale_n,
    const float* __restrict__ shift_n,
    const bf16* __restrict__ addF,
    int act,
    bf16* __restrict__ vt,
    float* __restrict__ srow, long long szl, long long szh, long long sgm)
{
  constexpr int BM = MF*32, BN = NF*32;
  constexpr int CHA = BM/16, CH = (BM+BN)/16;
  static_assert(CH % 4 == 0, "chunks must divide among 4 waves");
  __shared__ bf16 Asm[BM][32];
  __shared__ bf16 Bsm[BN][32];
  const int tid = threadIdx.x;
  const int lane = tid & 63, wid = tid >> 6;
  const int wm = wid >> 1, wn = wid & 1;
  const int m0 = blockIdx.y*BM, n0 = blockIdx.x*BN;
  const int z = blockIdx.z;
  const long long zl = z & 7, zh = z >> 3;
  const bf16* Ab = A + zl*sA + zh*sA2;
  const bf16* Bb = Bt + zl*sB + zh*sB2;
  TC* Cb = C + zl*sC + zh*sC2;
  const bf16* Fb = addF ? addF + zl*sC + zh*sC2 : nullptr;

  f32x4 acc[MF][NF];
  f32x4 zero = {0.f, 0.f, 0.f, 0.f};
  #pragma unroll
  for (int m = 0; m < MF; ++m)
    #pragma unroll
    for (int n = 0; n < NF; ++n) acc[m][n] = zero;

  const int rchunk = lane >> 2;
  const int kchunk = (lane & 3) * 8;
  const int row16 = lane & 15, kq = (lane >> 4) * 8;

  for (int k0 = 0; k0 < K; k0 += 32){
    #pragma unroll
    for (int cc = 0; cc < CH/4; ++cc){
      int c = wid + cc*4;
      if (c < CHA){
        int row = c*16 + rchunk;
        gload_lds(Ab + (long long)(m0+row)*lda + k0 + kchunk, &Asm[c*16][0]);
      } else {
        int row = (c-CHA)*16 + rchunk;
        gload_lds(Bb + (long long)(n0+row)*ldb + k0 + kchunk, &Bsm[(c-CHA)*16][0]);
      }
    }
    __syncthreads();
    bf16x8 af[MF], bfr[NF];
    #pragma unroll
    for (int m = 0; m < MF; ++m)
      af[m] = *(const bf16x8*)&Asm[wm*(MF*16) + m*16 + row16][kq];
    #pragma unroll
    for (int n = 0; n < NF; ++n)
      bfr[n] = *(const bf16x8*)&Bsm[wn*(NF*16) + n*16 + row16][kq];
    #pragma unroll
    for (int m = 0; m < MF; ++m)
      #pragma unroll
      for (int n = 0; n < NF; ++n)
        acc[m][n] = __builtin_amdgcn_mfma_f32_16x16x32_bf16(af[m], bfr[n], acc[m][n], 0, 0, 0);
    __syncthreads();
  }

  if constexpr (EXP){
    // e = exp(alpha*acc); store; butterfly row-sum over lane&15; atomicAdd per row.
    #pragma unroll
    for (int m = 0; m < MF; ++m){
      int gmb = m0 + wm*(MF*16) + m*16 + (lane >> 4)*4;
      float rowsum[4] = {0.f, 0.f, 0.f, 0.f};
      #pragma unroll
      for (int n = 0; n < NF; ++n){
        int gn = n0 + wn*(NF*16) + n*16 + row16;
        #pragma unroll
        for (int r = 0; r < 4; ++r){
          float e = __expf(acc[m][n][r] * alpha);
          long long idx = (long long)(gmb + r)*ldc + gn;
          if constexpr (__is_same(TC, float)) Cb[idx] = e; else Cb[idx] = f2b(e);
          rowsum[r] += e;
        }
      }
      #pragma unroll
      for (int r = 0; r < 4; ++r){
        float s = rowsum[r];
        #pragma unroll
        for (int o = 1; o < 16; o <<= 1) s += __shfl_xor(s, o, 64);
        if ((lane & 15) == 0)
          atomicAdd(&srow[zl*szl + zh*szh + (long long)(gmb + r)*sgm], s);
      }
    }
    return;
  }

  #pragma unroll
  for (int m = 0; m < MF; ++m){
    #pragma unroll
    for (int n = 0; n < NF; ++n){
      int gn = n0 + wn*(NF*16) + n*16 + row16;
      float bn_ = bias_n ? b2f(bias_n[gn]) : 0.f;
      float sc = scale_n ? scale_n[gn] : 1.f;
      float sh = shift_n ? shift_n[gn] : 0.f;
      int gmb = m0 + wm*(MF*16) + m*16 + (lane >> 4)*4;
      float vals[4];
      #pragma unroll
      for (int r = 0; r < 4; ++r){
        int gm = gmb + r;
        float v = acc[m][n][r] * alpha + bn_;
        v = v * sc + sh;
        if (act) v = gelu_f(v);
        long long idx = (long long)gm*ldc + gn;
        if (Fb) v += b2f(Fb[idx]);
        if (beta){
          float old;
          if constexpr (__is_same(TC, float)) old = Cb[idx]; else old = b2f(Cb[idx]);
          v += old;
        }
        if constexpr (__is_same(TC, float)) Cb[idx] = v; else Cb[idx] = f2b(v);
        vals[r] = v;
      }
      if (vt && gn >= 1024){
        int h = (gn - 1024) >> 6, d = (gn - 1024) & 63;
        int bb = gmb >> 10, nn = gmb & 1023;
        ushort4 o;
        o.x = f2bits(vals[0]); o.y = f2bits(vals[1]);
        o.z = f2bits(vals[2]); o.w = f2bits(vals[3]);
        *(ushort4*)&vt[(((long long)bb*8 + h)*64 + d)*1024 + nn] = o;
      }
    }
  }
}

template<int MF, int NF, typename TC>
static void gmfma_x(hipStream_t st, int z, int M, int N, int K,
                    const bf16* A, int lda, long long sA, long long sA2,
                    const bf16* Bt, int ldb, long long sB, long long sB2,
                    TC* C, int ldc, long long sC, long long sC2,
                    float alpha = 1.f, int beta = 0,
                    const bf16* bias_n = nullptr,
                    const float* scale_n = nullptr, const float* shift_n = nullptr,
                    const bf16* addF = nullptr, int act = 0, bf16* vt = nullptr)
{
  dim3 g(N/(NF*32), M/(MF*32), z);
  gmfma_k<MF,NF,TC,0><<<g, 256, 0, st>>>(M,N,K,A,lda,sA,sA2,Bt,ldb,sB,sB2,C,ldc,sC,sC2,
                                         alpha,beta,bias_n,scale_n,shift_n,addF,act,vt,
                                         nullptr,0,0,0);
}

template<int MF, int NF, typename TC>
static void gmfma(hipStream_t st, int z, int M, int N, int K,
                  const bf16* A, int lda, long long sA,
                  const bf16* Bt, int ldb, long long sB,
                  TC* C, int ldc, long long sC,
                  float alpha = 1.f, int beta = 0,
                  const bf16* bias_n = nullptr,
                  const float* scale_n = nullptr, const float* shift_n = nullptr,
                  const bf16* addF = nullptr, int act = 0, bf16* vt = nullptr)
{
  gmfma_x<MF,NF,TC>(st, z, M, N, K, A, lda, sA, 8*sA, Bt, ldb, sB, 8*sB,
                    C, ldc, sC, 8*sC, alpha, beta, bias_n, scale_n, shift_n, addF, act, vt);
}

template<int MF, int NF, typename TC>
static void gmfma_exp(hipStream_t st, int z, int M, int N, int K,
                      const bf16* A, int lda, long long sA, long long sA2,
                      const bf16* Bt, int ldb, long long sB, long long sB2,
                      TC* C, int ldc, long long sC, long long sC2,
                      float alpha,
                      float* srow, long long szl, long long szh, long long sgm)
{
  dim3 g(N/(NF*32), M/(MF*32), z);
  gmfma_k<MF,NF,TC,1><<<g, 256, 0, st>>>(M,N,K,A,lda,sA,sA2,Bt,ldb,sB,sB2,C,ldc,sC,sC2,
                                         alpha,0,nullptr,nullptr,nullptr,nullptr,0,nullptr,
                                         srow,szl,szh,sgm);
}

// ---------- LayerNorm fp32 -> bf16 ----------
__global__ __launch_bounds__(256) void ln_k(const float* __restrict__ X, bf16* __restrict__ Y,
                                            const bf16* __restrict__ w, const bf16* __restrict__ b){
  long long row = blockIdx.x;
  const float* x = X + row*512;
  bf16* y = Y + row*512;
  int tid = threadIdx.x;
  float v0 = x[tid], v1 = x[tid+256];
  float mean = block_reduce<false>(v0+v1) * (1.f/512.f);
  float msq  = block_reduce<false>(v0*v0+v1*v1) * (1.f/512.f);
  float var = msq - mean*mean;
  float rs = rsqrtf(var + 1e-5f);
  y[tid]     = f2b((v0-mean)*rs*b2f(w[tid])     + b2f(b[tid]));
  y[tid+256] = f2b((v1-mean)*rs*b2f(w[tid+256]) + b2f(b[tid+256]));
}

// ---------- fused normalize + 3x3 MFMA conv (input = exp scores, SROW = row sums) ----------
// grid (2 j-halves, 128 i-tiles, NB); 8-row tiles; 8 chunks of 64 cols.
__device__ __forceinline__ int csw(int col){ return col ^ ((col >> 3) & 7); }

__global__ __launch_bounds__(256) void convNorm_k(
    const bf16* __restrict__ Sp, bf16* __restrict__ Pout,
    const bf16* __restrict__ Wr, const bf16* __restrict__ bias,
    const float* __restrict__ Srow,
    long long bstride)
{
  __shared__ bf16 tile[10][66][8];
  __shared__ float irow[10][8];
  long long b = blockIdx.z;
  int i0 = blockIdx.y*8;
  int jh0 = blockIdx.x*512;
  int tid = threadIdx.x;
  const bf16* src = Sp + b*bstride;

  if (tid < 80){
    int r = tid >> 3, h = tid & 7;
    int gi = i0 + r - 1;
    float iv = 0.f;
    if ((unsigned)gi < 1024u) iv = 1.f / Srow[(b*1024 + gi)*8 + h];
    irow[r][h] = iv;
  }

  int lane = tid & 63, wid = tid >> 6;
  int row16 = lane & 15, q = lane >> 4;
  bf16x8 wf0 = *(const bf16x8*)&Wr[row16*96 +  0 + q*8];
  bf16x8 wf1 = *(const bf16x8*)&Wr[row16*96 + 32 + q*8];
  bf16x8 wf2 = *(const bf16x8*)&Wr[row16*96 + 64 + q*8];
  float bv = (row16 < 8) ? b2f(bias[row16]) : 0.f;

  for (int c = 0; c < 8; ++c){
    int base = jh0 + c*64;
    __syncthreads();
    for (int t = tid; t < 320; t += 256){
      int row = t >> 5, rem = t & 31;
      int hp = rem >> 3, seg = rem & 7;
      int gi = i0 + row - 1;
      int g0 = base + seg*8;
      unsigned ov[8];
      if ((unsigned)gi < 1024u){
        const bf16* p0 = src + (long long)(2*hp)*1048576 + (long long)gi*1024 + g0;
        bf16x8 a0 = *(const bf16x8*)p0;
        bf16x8 a1 = *(const bf16x8*)(p0 + 1048576);
        float i0v = irow[row][2*hp];
        float i1v = irow[row][2*hp+1];
        #pragma unroll
        for (int k = 0; k < 8; ++k){
          float e0 = bits2f((unsigned)(unsigned short)a0[k]) * i0v;
          float e1 = bits2f((unsigned)(unsigned short)a1[k]) * i1v;
          ov[k] = (unsigned)f2bits(e0) | ((unsigned)f2bits(e1) << 16);
        }
      } else {
        #pragma unroll
        for (int k = 0; k < 8; ++k) ov[k] = 0u;
      }
      #pragma unroll
      for (int k = 0; k < 8; ++k)
        *(unsigned*)&tile[row][csw(1 + seg*8 + k)][2*hp] = ov[k];
    }
    if (tid < 40){
      int row = tid >> 2, hp = tid & 3;
      int gi = i0 + row - 1;
      unsigned L = 0u, R = 0u;
      if ((unsigned)gi < 1024u){
        long long rb = (long long)gi*1024;
        int cl = base - 1, cr = base + 64;
        float i0v = irow[row][2*hp];
        float i1v = irow[row][2*hp+1];
        if (cl >= 0){
          float e0 = b2f(src[(long long)(2*hp)*1048576 + rb + cl]) * i0v;
          float e1 = b2f(src[(long long)(2*hp+1)*1048576 + rb + cl]) * i1v;
          L = (unsigned)f2bits(e0) | ((unsigned)f2bits(e1) << 16);
        }
        if (cr < 1024){
          float e0 = b2f(src[(long long)(2*hp)*1048576 + rb + cr]) * i0v;
          float e1 = b2f(src[(long long)(2*hp+1)*1048576 + rb + cr]) * i1v;
          R = (unsigned)f2bits(e0) | ((unsigned)f2bits(e1) << 16);
        }
      }
      *(unsigned*)&tile[row][csw(0)][2*hp] = L;
      *(unsigned*)&tile[row][csw(65)][2*hp] = R;
    }
    __syncthreads();
    #pragma unroll
    for (int rr = 0; rr < 2; ++rr){
      int ii = rr*4 + wid;
      f32x4 zero = {0.f,0.f,0.f,0.f};
      f32x4 acc[4] = {zero,zero,zero,zero};
      #pragma unroll
      for (int ks = 0; ks < 3; ++ks){
        int tap = ks*4 + q;
        int tcl = tap > 8 ? 0 : tap;
        int di = tcl/3, dj = tcl - di*3;
        bf16x8 wsel = ks==0 ? wf0 : (ks==1 ? wf1 : wf2);
        #pragma unroll
        for (int mf = 0; mf < 4; ++mf){
          bf16x8 af = *(const bf16x8*)&tile[ii+di][csw(mf*16 + row16 + dj)][0];
          acc[mf] = __builtin_amdgcn_mfma_f32_16x16x32_bf16(af, wsel, acc[mf], 0, 0, 0);
        }
      }
      if (row16 < 8){
        bf16* dst = Pout + b*bstride + (long long)row16*1048576 + (long long)(i0+ii)*1024;
        #pragma unroll
        for (int mf = 0; mf < 4; ++mf){
          int j = base + mf*16 + q*4;
          ushort4 o;
          o.x = f2bits(acc[mf][0] + bv);
          o.y = f2bits(acc[mf][1] + bv);
          o.z = f2bits(acc[mf][2] + bv);
          o.w = f2bits(acc[mf][3] + bv);
          *(ushort4*)&dst[j] = o;
        }
      }
    }
  }
}

// ---------- 3x3 conv, 1 ch, normalize-during-staging, bf16 TRANSPOSED out ----------
__global__ __launch_bounds__(256) void conv_spec_k(const float* __restrict__ in, bf16* __restrict__ out,
                                                   const bf16* __restrict__ w, const bf16* __restrict__ bias,
                                                   const float* __restrict__ SSrow){
  __shared__ float ti[66][67];
  __shared__ bf16 toutT[64][65];
  __shared__ float sis[66];
  int b = blockIdx.z;
  int i0 = blockIdx.y*64, j0 = blockIdx.x*64;
  int tid = threadIdx.x;
  const float* ib = in + (long long)b*262144;
  if (tid < 66){
    int gi = i0 + tid - 1;
    float iv = 0.f;
    if ((unsigned)gi < 512u) iv = 1.f / SSrow[b*512 + gi];
    sis[tid] = iv;
  }
  __syncthreads();
  for (int t = tid; t < 66*66; t += 256){
    int r = t / 66, cc = t - r*66;
    int gi = i0 + r - 1, gj = j0 + cc - 1;
    float v = 0.f;
    if ((unsigned)gi < 512u && (unsigned)gj < 512u)
      v = ib[gi*512 + gj] * sis[r];
    ti[r][cc] = v;
  }
  __syncthreads();
  float w9[9], bv = b2f(bias[0]);
  #pragma unroll
  for (int d = 0; d < 9; ++d) w9[d] = b2f(w[d]);
  int ii = tid & 63;
  #pragma unroll
  for (int q = 0; q < 16; ++q){
    int jj = (tid >> 6)*16 + q;
    float acc = bv;
    #pragma unroll
    for (int di = 0; di < 3; ++di)
      #pragma unroll
      for (int dj = 0; dj < 3; ++dj)
        acc += w9[di*3+dj] * ti[ii+di][jj+dj];
    toutT[jj][ii] = f2b(acc);
  }
  __syncthreads();
  #pragma unroll
  for (int q = 0; q < 16; ++q){
    int jj = (tid >> 6)*16 + q;
    out[(long long)b*262144 + (j0+jj)*512 + i0 + (tid & 63)] = toutT[jj][tid & 63];
  }
}

// ---------- depthwise 3x3; Hbuf (b,n,c) bf16 -> T1 (b,n,c) bf16 ----------
__global__ __launch_bounds__(256) void dwconv_k(const bf16* __restrict__ H2, bf16* __restrict__ T1,
                                                const bf16* __restrict__ w, const bf16* __restrict__ bias){
  int p = blockIdx.x*256 + threadIdx.x;
  int cp = p & 255;
  int n = (p >> 8) & 1023;
  int b = p >> 18;
  int c0 = cp*2;
  int wi = n >> 5, hg = n & 31;
  float a0 = b2f(bias[c0]), a1 = b2f(bias[c0+1]);
  #pragma unroll
  for (int di = 0; di < 3; ++di){
    int gw = wi + di - 1;
    if ((unsigned)gw >= 32u) continue;
    #pragma unroll
    for (int dj = 0; dj < 3; ++dj){
      int gh = hg + dj - 1;
      if ((unsigned)gh >= 32u) continue;
      unsigned hv = *(const unsigned*)&H2[((long long)b*1024 + (gw*32+gh))*512 + c0];
      float w0 = b2f(w[c0*9 + di*3 + dj]);
      float w1 = b2f(w[(c0+1)*9 + di*3 + dj]);
      a0 += w0 * bits2f(hv & 0xffffu);
      a1 += w1 * bits2f(hv >> 16);
    }
  }
  bf16 h0 = f2b(a0), h1 = f2b(a1);
  unsigned o = ((unsigned)*(unsigned short*)&h1 << 16) | (unsigned)*(unsigned short*)&h0;
  *(unsigned*)&T1[((long long)b*1024 + n)*512 + c0] = o;
}

// ---------- fold pw bias + BN(eval), all layers ----------
__global__ void bnaff_all_k(const bf16* __restrict__ pwb, const bf16* __restrict__ g,
                            const bf16* __restrict__ bb, const bf16* __restrict__ m,
                            const bf16* __restrict__ v, float* __restrict__ BNAFF){
  int l = blockIdx.x, o = threadIdx.x;
  float s = b2f(g[l*256+o]) * rsqrtf(b2f(v[l*256+o]) + 1e-5f);
  BNAFF[l*512 + o] = s;
  BNAFF[l*512 + 256 + o] = (b2f(pwb[l*256+o]) - b2f(m[l*256+o])) * s + b2f(bb[l*256+o]);
}

// ---------- HbufT[b][c][n] = Hbuf[b][n][c] ----------
__global__ __launch_bounds__(256) void htrans_k(const bf16* __restrict__ Hb, bf16* __restrict__ HT){
  __shared__ bf16 t[64][65];
  int b = blockIdx.z;
  int n0 = blockIdx.x*64, c0 = blockIdx.y*64;
  int lane = threadIdx.x & 63, quad = threadIdx.x >> 6;
  #pragma unroll
  for (int k = 0; k < 16; ++k){
    int r = quad*16 + k;
    t[r][lane] = Hb[((long long)b*1024 + n0 + r)*512 + c0 + lane];
  }
  __syncthreads();
  #pragma unroll
  for (int k = 0; k < 16; ++k){
    int c = quad*16 + k;
    HT[(long long)b*524288 + (long long)(c0+c)*1024 + n0 + lane] = t[lane][c];
  }
}

// ---------- orchestration ----------
extern "C" void kernel_launch(void* const* d_in, const int* in_sizes, int n_in,
                              void* d_out, int out_size, void* d_ws, size_t ws_size,
                              hipStream_t stream)
{
  (void)in_sizes; (void)n_in; (void)out_size;

  const bool big = ws_size >= 207000000ull;
  const long long ATTN_SZ = big ? 33554432LL : 8388608LL;

  // ---- arena ----
  float* X     = (float*)d_ws;
  bf16*  WBsm  = (bf16*)(X + 2097152);
  bf16*  WqkvT = WBsm  + 2139648;
  bf16*  WoutT = WqkvT + 3145728;
  bf16*  WqsT  = WoutT + 1048576;
  bf16*  Hbuf  = WqsT  + 8388608;
  bf16*  HbufT = Hbuf  + 2097152;
  bf16*  QKV   = HbufT + 2097152;
  bf16*  Vt    = QKV   + 6291456;
  bf16*  OUTH  = Vt    + 2097152;
  bf16*  OUT   = OUTH  + 2097152;
  bf16*  ATTN  = OUT   + 2097152;
  bf16*  ATTNC = ATTN  + ATTN_SZ;
  float* BNAFF = (float*)(ATTNC + ATTN_SZ);
  bf16*  WR    = (bf16*)(BNAFF + 2048);
  float* SROW  = (float*)(WR + 6144);
  float* SSROW = SROW + 32768;
  int*   FLAG  = (int*)(SSROW + 2048);

  float* ASPEC   = (float*)OUTH;
  bf16*  ASPECCT = ATTNC;
  bf16*  T1 = ATTN;
  bf16*  T3 = ATTN + 2097152;
  bf16*  T2 = ATTNC + 2097152;
  bf16*  SQK = ATTN;

  // ---- small-weight arena ----
  static const int widx[21] = {1,2,5,6,7,9,10,11,12,13,14,15,16,17,18,19,20,21,22,23,24};
  static const long long wsz[21] = {2048,2048,2048,2304,32,36,4,2048,2048,18432,2048,
                                    524288,1024,1024,1024,1024,1024,524288,2048,1048576,2048};
  WCvt21 wc;
  long long cum = 0;
  bf16* wp[21];
  for (int t = 0; t < 21; ++t){
    wc.src[t] = d_in[widx[t]];
    wc.cum[t] = cum;
    wp[t] = WBsm + cum;
    cum += wsz[t];
  }
  wc.cum[21] = cum;

  bf16 *w_ln1w = wp[0],  *w_ln1b = wp[1],  *w_bout = wp[2],  *w_spw = wp[3];
  bf16 *w_spb  = wp[4],  *w_specw= wp[5],  *w_specb= wp[6],  *w_ln2w= wp[7];
  bf16 *w_ln2b = wp[8],  *w_dww  = wp[9],  *w_dwb  = wp[10], *w_pww = wp[11];
  bf16 *w_pwb  = wp[12], *w_bng  = wp[13], *w_bnb  = wp[14], *w_bnm = wp[15];
  bf16 *w_bnv  = wp[16], *w_c1w  = wp[17], *w_c1b  = wp[18], *w_c2w = wp[19];
  bf16 *w_c2b  = wp[20];

  // ---- setup ----
  detect_k<<<1, 256, 0, stream>>>((const unsigned*)d_in[0], FLAG);
  cvt_x_k<<<8192, 256, 0, stream>>>(d_in[0], X, FLAG);
  cvt_w_k<<<(int)((cum + 255)/256), 256, 0, stream>>>(wc, WBsm, cum, FLAG);
  wtrans_k<<<dim3(8,24,4), 256, 0, stream>>>(d_in[3], WqkvT, 1536, 512, 786432LL, 786432LL, FLAG);
  wtrans_k<<<dim3(8, 8,4), 256, 0, stream>>>(d_in[4], WoutT,  512, 512, 262144LL, 262144LL, FLAG);
  wtrans_k<<<dim3(16,32,4),256, 0, stream>>>(d_in[8], WqsT,  3072,1024, 3145728LL,2097152LL, FLAG);
  bnaff_all_k<<<4, 256, 0, stream>>>(w_pwb, w_bng, w_bnb, w_bnm, w_bnv, BNAFF);
  wprep_k<<<4, 256, 0, stream>>>(w_spw, WR);

  for (int l = 0; l < 4; ++l){
    zero_k<<<136, 256, 0, stream>>>(SROW, 34816);
    // --- spatial attention ---
    ln_k<<<4096, 256, 0, stream>>>(X, Hbuf, w_ln1w + l*512, w_ln1b + l*512);
    gmfma<2,4,bf16>(stream, 1, 4096, 1536, 512,
        Hbuf, 512, 0, WqkvT + (long long)l*786432, 512, 0, QKV, 1536, 0,
        1.f, 0, nullptr, nullptr, nullptr, nullptr, 0, Vt);
    if (big){
      // srow index = h*szl + b*szh + i*sgm = h + b*8192 + i*8
      gmfma_exp<4,4,bf16>(stream, 32, 1024, 1024, 64,
          QKV, 1536, 64, 1572864, QKV + 512, 1536, 64, 1572864,
          ATTN, 1024, 1048576, 8388608, 0.125f,
          SROW, 1, 8192, 8);
      convNorm_k<<<dim3(2,128,4), 256, 0, stream>>>(ATTN, ATTNC, WR + l*1536, w_spb + l*8,
                                                    SROW, 8388608LL);
      gmfma_x<2,2,bf16>(stream, 32, 1024, 64, 1024,
          ATTNC, 1024, 1048576, 8388608, Vt, 1024, 65536, 524288,
          OUTH, 512, 64, 524288);
    } else {
      for (int b = 0; b < 4; ++b){
        bf16* qkvb = QKV + (long long)b*1572864;
        gmfma_exp<4,4,bf16>(stream, 8, 1024, 1024, 64,
            qkvb, 1536, 64, 8*64, qkvb + 512, 1536, 64, 8*64,
            ATTN, 1024, 1048576, 8*1048576, 0.125f,
            SROW + b*8192, 1, 0, 8);
        convNorm_k<<<dim3(2,128,1), 256, 0, stream>>>(ATTN, ATTNC, WR + l*1536, w_spb + l*8,
                                                      SROW + b*8192, 8388608LL);
        gmfma<2,2,bf16>(stream, 8, 1024, 64, 1024,
            ATTNC, 1024, 1048576, Vt + (long long)b*524288, 1024, 65536,
            OUTH + (long long)b*524288, 512, 64);
      }
    }
    gmfma<2,2,bf16>(stream, 1, 4096, 512, 512,
        OUTH, 512, 0, WoutT + (long long)l*262144, 512, 0, OUT, 512, 0,
        1.f, 0, w_bout + l*512);
    // --- spectral attention ---
    htrans_k<<<dim3(16,8,4), 256, 0, stream>>>(Hbuf, HbufT);
    gmfma<2,2,bf16>(stream, 4, 512, 2048, 1024,
        HbufT, 1024, 524288, WqsT + (long long)l*2097152, 1024, 0, SQK, 2048, 1048576);
    gmfma_exp<2,2,float>(stream, 4, 512, 512, 1024,
        SQK, 2048, 1048576, 8*1048576, SQK + 1024, 2048, 1048576, 8*1048576,
        ASPEC, 512, 262144, 8*262144, 0.125f,
        SSROW, 512, 0, 1);
    conv_spec_k<<<dim3(8,8,4), 256, 0, stream>>>(ASPEC, ASPECCT, w_specw + l*9, w_specb + l,
                                                 SSROW);
    gmfma<2,2,float>(stream, 4, 1024, 512, 512,
        OUT, 512, 524288, ASPECCT, 512, 262144, X, 512, 524288, 1.f, 1);
    // --- conv FFN ---
    ln_k<<<4096, 256, 0, stream>>>(X, Hbuf, w_ln2w + l*512, w_ln2b + l*512);
    dwconv_k<<<4096, 256, 0, stream>>>(Hbuf, T1, w_dww + l*4608, w_dwb + l*512);
    gmfma<2,2,bf16>(stream, 4, 1024, 256, 512,
        T1, 512, 524288, w_pww + (long long)l*131072, 512, 0, T2, 256, 262144,
        1.f, 0, nullptr, BNAFF + l*512, BNAFF + l*512 + 256);
    gmfma<2,2,bf16>(stream, 4, 1024, 512, 256,
        T2, 256, 262144, w_c1w + (long long)l*131072, 256, 0, T3, 512, 524288,
        1.f, 0, w_c1b + l*512, nullptr, nullptr, nullptr, 1);
    gmfma<2,2,float>(stream, 4, 1024, 512, 512,
        T3, 512, 524288, w_c2w + (long long)l*262144, 512, 0, X, 512, 524288,
        1.f, 1, w_c2b + l*512, nullptr, nullptr, Hbuf, 1);
  }

  store_out_k<<<8192, 256, 0, stream>>>(X, d_out, FLAG);
}

// Round 19
// 1126.151 us; speedup vs baseline: 1.2294x; 1.0167x over previous
//
#include <hip/hip_runtime.h>
#include <hip/hip_bf16.h>

typedef __hip_bfloat16 bf16;
typedef __attribute__((ext_vector_type(8))) short bf16x8;
typedef __attribute__((ext_vector_type(4))) float f32x4;

// ---------- helpers ----------
__device__ __forceinline__ float b2f(bf16 v){ return __bfloat162float(v); }
__device__ __forceinline__ bf16 f2b(float v){ return __float2bfloat16(v); }
__device__ __forceinline__ float bits2f(unsigned u){ return __uint_as_float(u << 16); }
__device__ __forceinline__ unsigned short f2bits(float v){ bf16 t = __float2bfloat16(v); return *(unsigned short*)&t; }

__device__ __forceinline__ float gelu_f(float x){
  return 0.5f * x * (1.f + erff(x * 0.7071067811865475f));
}

__device__ __forceinline__ void gload_lds(const void* g, void* l){
  __builtin_amdgcn_global_load_lds((const __attribute__((address_space(1))) void*)g,
                                   (__attribute__((address_space(3))) void*)l, 16, 0, 0);
}

template<bool MAX>
__device__ __forceinline__ float block_reduce(float v){
  __shared__ float s[4];
  #pragma unroll
  for (int o = 32; o > 0; o >>= 1){
    float t = __shfl_down(v, o, 64);
    v = MAX ? fmaxf(v, t) : (v + t);
  }
  int lane = threadIdx.x & 63, w = threadIdx.x >> 6;
  __syncthreads();
  if (lane == 0) s[w] = v;
  __syncthreads();
  return MAX ? fmaxf(fmaxf(s[0], s[1]), fmaxf(s[2], s[3]))
             : (s[0] + s[1] + s[2] + s[3]);
}

// ---------- dtype detect + converters ----------
__global__ void detect_k(const unsigned* __restrict__ x, int* __restrict__ flag){
  __shared__ int cnt[256];
  int tid = threadIdx.x;
  int c = 0;
  for (int i = tid; i < 4096; i += 256){
    unsigned h = x[i] & 0xffffu;
    int e = (int)((h >> 7) & 0xff);
    if (h == 0u || (e >= 100 && e <= 133)) c++;
  }
  cnt[tid] = c;
  __syncthreads();
  for (int o = 128; o > 0; o >>= 1){ if (tid < o) cnt[tid] += cnt[tid+o]; __syncthreads(); }
  if (tid == 0) *flag = (cnt[0] < 2048) ? 1 : 0;
}

__global__ __launch_bounds__(256) void cvt_x_k(const void* __restrict__ src,
                                               float* __restrict__ X,
                                               const int* __restrict__ flag){
  int p = blockIdx.x*256 + threadIdx.x;
  X[p] = (*flag) ? ((const float*)src)[p]
                 : __bfloat162float(((const bf16*)src)[p]);
}

struct WCvt21 { const void* src[21]; long long cum[22]; };

__global__ __launch_bounds__(256) void cvt_w_k(WCvt21 a, bf16* __restrict__ WB,
                                               long long total, const int* __restrict__ flag){
  long long i = (long long)blockIdx.x*256 + threadIdx.x;
  if (i >= total) return;
  int t = 0;
  while (a.cum[t+1] <= i) t++;
  long long e = i - a.cum[t];
  WB[i] = (*flag) ? __float2bfloat16(((const float*)a.src[t])[e])
                  : ((const bf16*)a.src[t])[e];
}

// transpose + convert weight: dst[z][c][r] = src[z][r][c], tiles 64x64
__global__ __launch_bounds__(256) void wtrans_k(const void* __restrict__ src, bf16* __restrict__ dst,
                                                int ld_src, int ldd, long long sSrc, long long sDst,
                                                const int* __restrict__ flag){
  __shared__ bf16 t[64][65];
  int z = blockIdx.z;
  int r0 = blockIdx.x*64, c0 = blockIdx.y*64;
  int lane = threadIdx.x & 63, quad = threadIdx.x >> 6;
  const float* sf = (const float*)src;
  const bf16* sb = (const bf16*)src;
  int fl = *flag;
  #pragma unroll
  for (int k = 0; k < 16; ++k){
    int r = quad*16 + k;
    long long idx = z*sSrc + (long long)(r0+r)*ld_src + c0 + lane;
    float v = fl ? sf[idx] : b2f(sb[idx]);
    t[r][lane] = f2b(v);
  }
  __syncthreads();
  #pragma unroll
  for (int k = 0; k < 16; ++k){
    int c = quad*16 + k;
    dst[z*sDst + (long long)(c0+c)*ldd + r0 + lane] = t[lane][c];
  }
}

// conv-attn weight shuffle: Wr[l][16][96]; Wr[l][ho][tap*8+hi] = spw[l][ho][hi][tap], 0-padded
__global__ void wprep_k(const bf16* __restrict__ spw, bf16* __restrict__ Wr){
  int l = blockIdx.x;
  for (int t = threadIdx.x; t < 1536; t += 256){
    int ho = t / 96, k = t - ho*96;
    float v = 0.f;
    if (ho < 8 && k < 72){
      int tap = k >> 3, hi = k & 7;
      v = b2f(spw[l*576 + ho*72 + hi*9 + tap]);
    }
    Wr[l*1536 + t] = f2b(v);
  }
}

__global__ __launch_bounds__(256) void store_out_k(const float* __restrict__ X,
                                                   void* __restrict__ out,
                                                   const int* __restrict__ flag){
  int p = blockIdx.x*256 + threadIdx.x;
  if (*flag) ((float*)out)[p] = X[p];
  else       ((bf16*)out)[p] = f2b(X[p]);
}

__global__ __launch_bounds__(256) void zero_k(float* __restrict__ p, int n){
  int i = blockIdx.x*256 + threadIdx.x;
  if (i < n) p[i] = 0.f;
}

// ---------- MFMA GEMM ----------
// C[z] = epi( alpha * A(MxK,row) x Bt(NxK,row)^T ); z decomposes as (z&7, z>>3)
// EXP=1: C = exp(alpha*acc) (bf16/f32), row sums atomically added to srow.
template<int MF, int NF, typename TC, int EXP>
__global__ __launch_bounds__(256) void gmfma_k(
    int M, int N, int K,
    const bf16* __restrict__ A, int lda, long long sA, long long sA2,
    const bf16* __restrict__ Bt, int ldb, long long sB, long long sB2,
    TC* __restrict__ C, int ldc, long long sC, long long sC2,
    float alpha, int beta,
    const bf16* __restrict__ bias_n,
    const float* __restrict__ scale_n,
    const float* __restrict__ shift_n,
    const bf16* __restrict__ addF,
    int act,
    bf16* __restrict__ vt,
    float* __restrict__ srow, long long szl, long long szh, long long sgm)
{
  constexpr int BM = MF*32, BN = NF*32;
  constexpr int CHA = BM/16, CH = (BM+BN)/16;
  static_assert(CH % 4 == 0, "chunks must divide among 4 waves");
  __shared__ bf16 Asm[BM][32];
  __shared__ bf16 Bsm[BN][32];
  const int tid = threadIdx.x;
  const int lane = tid & 63, wid = tid >> 6;
  const int wm = wid >> 1, wn = wid & 1;
  const int m0 = blockIdx.y*BM, n0 = blockIdx.x*BN;
  const int z = blockIdx.z;
  const long long zl = z & 7, zh = z >> 3;
  const bf16* Ab = A + zl*sA + zh*sA2;
  const bf16* Bb = Bt + zl*sB + zh*sB2;
  TC* Cb = C + zl*sC + zh*sC2;
  const bf16* Fb = addF ? addF + zl*sC + zh*sC2 : nullptr;

  f32x4 acc[MF][NF];
  f32x4 zero = {0.f, 0.f, 0.f, 0.f};
  #pragma unroll
  for (int m = 0; m < MF; ++m)
    #pragma unroll
    for (int n = 0; n < NF; ++n) acc[m][n] = zero;

  const int rchunk = lane >> 2;
  const int kchunk = (lane & 3) * 8;
  const int row16 = lane & 15, kq = (lane >> 4) * 8;

  for (int k0 = 0; k0 < K; k0 += 32){
    #pragma unroll
    for (int cc = 0; cc < CH/4; ++cc){
      int c = wid + cc*4;
      if (c < CHA){
        int row = c*16 + rchunk;
        gload_lds(Ab + (long long)(m0+row)*lda + k0 + kchunk, &Asm[c*16][0]);
      } else {
        int row = (c-CHA)*16 + rchunk;
        gload_lds(Bb + (long long)(n0+row)*ldb + k0 + kchunk, &Bsm[(c-CHA)*16][0]);
      }
    }
    __syncthreads();
    bf16x8 af[MF], bfr[NF];
    #pragma unroll
    for (int m = 0; m < MF; ++m)
      af[m] = *(const bf16x8*)&Asm[wm*(MF*16) + m*16 + row16][kq];
    #pragma unroll
    for (int n = 0; n < NF; ++n)
      bfr[n] = *(const bf16x8*)&Bsm[wn*(NF*16) + n*16 + row16][kq];
    #pragma unroll
    for (int m = 0; m < MF; ++m)
      #pragma unroll
      for (int n = 0; n < NF; ++n)
        acc[m][n] = __builtin_amdgcn_mfma_f32_16x16x32_bf16(af[m], bfr[n], acc[m][n], 0, 0, 0);
    __syncthreads();
  }

  if constexpr (EXP){
    // e = exp(alpha*acc); store; butterfly row-sum over lane&15; atomicAdd per row.
    #pragma unroll
    for (int m = 0; m < MF; ++m){
      int gmb = m0 + wm*(MF*16) + m*16 + (lane >> 4)*4;
      float rowsum[4] = {0.f, 0.f, 0.f, 0.f};
      #pragma unroll
      for (int n = 0; n < NF; ++n){
        int gn = n0 + wn*(NF*16) + n*16 + row16;
        #pragma unroll
        for (int r = 0; r < 4; ++r){
          float e = __expf(acc[m][n][r] * alpha);
          long long idx = (long long)(gmb + r)*ldc + gn;
          if constexpr (__is_same(TC, float)) Cb[idx] = e; else Cb[idx] = f2b(e);
          rowsum[r] += e;
        }
      }
      #pragma unroll
      for (int r = 0; r < 4; ++r){
        float s = rowsum[r];
        #pragma unroll
        for (int o = 1; o < 16; o <<= 1) s += __shfl_xor(s, o, 64);
        if ((lane & 15) == 0)
          atomicAdd(&srow[zl*szl + zh*szh + (long long)(gmb + r)*sgm], s);
      }
    }
    return;
  }

  #pragma unroll
  for (int m = 0; m < MF; ++m){
    #pragma unroll
    for (int n = 0; n < NF; ++n){
      int gn = n0 + wn*(NF*16) + n*16 + row16;
      float bn_ = bias_n ? b2f(bias_n[gn]) : 0.f;
      float sc = scale_n ? scale_n[gn] : 1.f;
      float sh = shift_n ? shift_n[gn] : 0.f;
      int gmb = m0 + wm*(MF*16) + m*16 + (lane >> 4)*4;
      float vals[4];
      #pragma unroll
      for (int r = 0; r < 4; ++r){
        int gm = gmb + r;
        float v = acc[m][n][r] * alpha + bn_;
        v = v * sc + sh;
        if (act) v = gelu_f(v);
        long long idx = (long long)gm*ldc + gn;
        if (Fb) v += b2f(Fb[idx]);
        if (beta){
          float old;
          if constexpr (__is_same(TC, float)) old = Cb[idx]; else old = b2f(Cb[idx]);
          v += old;
        }
        if constexpr (__is_same(TC, float)) Cb[idx] = v; else Cb[idx] = f2b(v);
        vals[r] = v;
      }
      if (vt && gn >= 1024){
        int h = (gn - 1024) >> 6, d = (gn - 1024) & 63;
        int bb = gmb >> 10, nn = gmb & 1023;
        ushort4 o;
        o.x = f2bits(vals[0]); o.y = f2bits(vals[1]);
        o.z = f2bits(vals[2]); o.w = f2bits(vals[3]);
        *(ushort4*)&vt[(((long long)bb*8 + h)*64 + d)*1024 + nn] = o;
      }
    }
  }
}

template<int MF, int NF, typename TC>
static void gmfma_x(hipStream_t st, int z, int M, int N, int K,
                    const bf16* A, int lda, long long sA, long long sA2,
                    const bf16* Bt, int ldb, long long sB, long long sB2,
                    TC* C, int ldc, long long sC, long long sC2,
                    float alpha = 1.f, int beta = 0,
                    const bf16* bias_n = nullptr,
                    const float* scale_n = nullptr, const float* shift_n = nullptr,
                    const bf16* addF = nullptr, int act = 0, bf16* vt = nullptr)
{
  dim3 g(N/(NF*32), M/(MF*32), z);
  gmfma_k<MF,NF,TC,0><<<g, 256, 0, st>>>(M,N,K,A,lda,sA,sA2,Bt,ldb,sB,sB2,C,ldc,sC,sC2,
                                         alpha,beta,bias_n,scale_n,shift_n,addF,act,vt,
                                         nullptr,0,0,0);
}

template<int MF, int NF, typename TC>
static void gmfma(hipStream_t st, int z, int M, int N, int K,
                  const bf16* A, int lda, long long sA,
                  const bf16* Bt, int ldb, long long sB,
                  TC* C, int ldc, long long sC,
                  float alpha = 1.f, int beta = 0,
                  const bf16* bias_n = nullptr,
                  const float* scale_n = nullptr, const float* shift_n = nullptr,
                  const bf16* addF = nullptr, int act = 0, bf16* vt = nullptr)
{
  gmfma_x<MF,NF,TC>(st, z, M, N, K, A, lda, sA, 8*sA, Bt, ldb, sB, 8*sB,
                    C, ldc, sC, 8*sC, alpha, beta, bias_n, scale_n, shift_n, addF, act, vt);
}

template<int MF, int NF, typename TC>
static void gmfma_exp(hipStream_t st, int z, int M, int N, int K,
                      const bf16* A, int lda, long long sA, long long sA2,
                      const bf16* Bt, int ldb, long long sB, long long sB2,
                      TC* C, int ldc, long long sC, long long sC2,
                      float alpha,
                      float* srow, long long szl, long long szh, long long sgm)
{
  dim3 g(N/(NF*32), M/(MF*32), z);
  gmfma_k<MF,NF,TC,1><<<g, 256, 0, st>>>(M,N,K,A,lda,sA,sA2,Bt,ldb,sB,sB2,C,ldc,sC,sC2,
                                         alpha,0,nullptr,nullptr,nullptr,nullptr,0,nullptr,
                                         srow,szl,szh,sgm);
}

// ---------- LayerNorm fp32 -> bf16 ----------
__global__ __launch_bounds__(256) void ln_k(const float* __restrict__ X, bf16* __restrict__ Y,
                                            const bf16* __restrict__ w, const bf16* __restrict__ b){
  long long row = blockIdx.x;
  const float* x = X + row*512;
  bf16* y = Y + row*512;
  int tid = threadIdx.x;
  float v0 = x[tid], v1 = x[tid+256];
  float mean = block_reduce<false>(v0+v1) * (1.f/512.f);
  float msq  = block_reduce<false>(v0*v0+v1*v1) * (1.f/512.f);
  float var = msq - mean*mean;
  float rs = rsqrtf(var + 1e-5f);
  y[tid]     = f2b((v0-mean)*rs*b2f(w[tid])     + b2f(b[tid]));
  y[tid+256] = f2b((v1-mean)*rs*b2f(w[tid+256]) + b2f(b[tid+256]));
}

// ---------- fused normalize + 3x3 MFMA conv (input = exp scores, SROW = row sums) ----------
// grid (2 j-halves, 128 i-tiles, NB); 8-row tiles; 8 chunks of 64 cols.
__device__ __forceinline__ int csw(int col){ return col ^ ((col >> 3) & 7); }

__global__ __launch_bounds__(256) void convNorm_k(
    const bf16* __restrict__ Sp, bf16* __restrict__ Pout,
    const bf16* __restrict__ Wr, const bf16* __restrict__ bias,
    const float* __restrict__ Srow,
    long long bstride)
{
  __shared__ bf16 tile[10][66][8];
  __shared__ float irow[10][8];
  long long b = blockIdx.z;
  int i0 = blockIdx.y*8;
  int jh0 = blockIdx.x*512;
  int tid = threadIdx.x;
  const bf16* src = Sp + b*bstride;

  if (tid < 80){
    int r = tid >> 3, h = tid & 7;
    int gi = i0 + r - 1;
    float iv = 0.f;
    if ((unsigned)gi < 1024u) iv = 1.f / Srow[(b*1024 + gi)*8 + h];
    irow[r][h] = iv;
  }

  int lane = tid & 63, wid = tid >> 6;
  int row16 = lane & 15, q = lane >> 4;
  bf16x8 wf0 = *(const bf16x8*)&Wr[row16*96 +  0 + q*8];
  bf16x8 wf1 = *(const bf16x8*)&Wr[row16*96 + 32 + q*8];
  bf16x8 wf2 = *(const bf16x8*)&Wr[row16*96 + 64 + q*8];
  float bv = (row16 < 8) ? b2f(bias[row16]) : 0.f;

  for (int c = 0; c < 8; ++c){
    int base = jh0 + c*64;
    __syncthreads();
    for (int t = tid; t < 320; t += 256){
      int row = t >> 5, rem = t & 31;
      int hp = rem >> 3, seg = rem & 7;
      int gi = i0 + row - 1;
      int g0 = base + seg*8;
      unsigned ov[8];
      if ((unsigned)gi < 1024u){
        const bf16* p0 = src + (long long)(2*hp)*1048576 + (long long)gi*1024 + g0;
        bf16x8 a0 = *(const bf16x8*)p0;
        bf16x8 a1 = *(const bf16x8*)(p0 + 1048576);
        float i0v = irow[row][2*hp];
        float i1v = irow[row][2*hp+1];
        #pragma unroll
        for (int k = 0; k < 8; ++k){
          float e0 = bits2f((unsigned)(unsigned short)a0[k]) * i0v;
          float e1 = bits2f((unsigned)(unsigned short)a1[k]) * i1v;
          ov[k] = (unsigned)f2bits(e0) | ((unsigned)f2bits(e1) << 16);
        }
      } else {
        #pragma unroll
        for (int k = 0; k < 8; ++k) ov[k] = 0u;
      }
      #pragma unroll
      for (int k = 0; k < 8; ++k)
        *(unsigned*)&tile[row][csw(1 + seg*8 + k)][2*hp] = ov[k];
    }
    if (tid < 40){
      int row = tid >> 2, hp = tid & 3;
      int gi = i0 + row - 1;
      unsigned L = 0u, R = 0u;
      if ((unsigned)gi < 1024u){
        long long rb = (long long)gi*1024;
        int cl = base - 1, cr = base + 64;
        float i0v = irow[row][2*hp];
        float i1v = irow[row][2*hp+1];
        if (cl >= 0){
          float e0 = b2f(src[(long long)(2*hp)*1048576 + rb + cl]) * i0v;
          float e1 = b2f(src[(long long)(2*hp+1)*1048576 + rb + cl]) * i1v;
          L = (unsigned)f2bits(e0) | ((unsigned)f2bits(e1) << 16);
        }
        if (cr < 1024){
          float e0 = b2f(src[(long long)(2*hp)*1048576 + rb + cr]) * i0v;
          float e1 = b2f(src[(long long)(2*hp+1)*1048576 + rb + cr]) * i1v;
          R = (unsigned)f2bits(e0) | ((unsigned)f2bits(e1) << 16);
        }
      }
      *(unsigned*)&tile[row][csw(0)][2*hp] = L;
      *(unsigned*)&tile[row][csw(65)][2*hp] = R;
    }
    __syncthreads();
    #pragma unroll
    for (int rr = 0; rr < 2; ++rr){
      int ii = rr*4 + wid;
      f32x4 zero = {0.f,0.f,0.f,0.f};
      f32x4 acc[4] = {zero,zero,zero,zero};
      #pragma unroll
      for (int ks = 0; ks < 3; ++ks){
        int tap = ks*4 + q;
        int tcl = tap > 8 ? 0 : tap;
        int di = tcl/3, dj = tcl - di*3;
        bf16x8 wsel = ks==0 ? wf0 : (ks==1 ? wf1 : wf2);
        #pragma unroll
        for (int mf = 0; mf < 4; ++mf){
          bf16x8 af = *(const bf16x8*)&tile[ii+di][csw(mf*16 + row16 + dj)][0];
          acc[mf] = __builtin_amdgcn_mfma_f32_16x16x32_bf16(af, wsel, acc[mf], 0, 0, 0);
        }
      }
      if (row16 < 8){
        bf16* dst = Pout + b*bstride + (long long)row16*1048576 + (long long)(i0+ii)*1024;
        #pragma unroll
        for (int mf = 0; mf < 4; ++mf){
          int j = base + mf*16 + q*4;
          ushort4 o;
          o.x = f2bits(acc[mf][0] + bv);
          o.y = f2bits(acc[mf][1] + bv);
          o.z = f2bits(acc[mf][2] + bv);
          o.w = f2bits(acc[mf][3] + bv);
          *(ushort4*)&dst[j] = o;
        }
      }
    }
  }
}

// ---------- 3x3 conv, 1 ch, normalize-during-staging, bf16 TRANSPOSED out ----------
__global__ __launch_bounds__(256) void conv_spec_k(const float* __restrict__ in, bf16* __restrict__ out,
                                                   const bf16* __restrict__ w, const bf16* __restrict__ bias,
                                                   const float* __restrict__ SSrow){
  __shared__ float ti[66][67];
  __shared__ bf16 toutT[64][65];
  __shared__ float sis[66];
  int b = blockIdx.z;
  int i0 = blockIdx.y*64, j0 = blockIdx.x*64;
  int tid = threadIdx.x;
  const float* ib = in + (long long)b*262144;
  if (tid < 66){
    int gi = i0 + tid - 1;
    float iv = 0.f;
    if ((unsigned)gi < 512u) iv = 1.f / SSrow[b*512 + gi];
    sis[tid] = iv;
  }
  __syncthreads();
  for (int t = tid; t < 66*66; t += 256){
    int r = t / 66, cc = t - r*66;
    int gi = i0 + r - 1, gj = j0 + cc - 1;
    float v = 0.f;
    if ((unsigned)gi < 512u && (unsigned)gj < 512u)
      v = ib[gi*512 + gj] * sis[r];
    ti[r][cc] = v;
  }
  __syncthreads();
  float w9[9], bv = b2f(bias[0]);
  #pragma unroll
  for (int d = 0; d < 9; ++d) w9[d] = b2f(w[d]);
  int ii = tid & 63;
  #pragma unroll
  for (int q = 0; q < 16; ++q){
    int jj = (tid >> 6)*16 + q;
    float acc = bv;
    #pragma unroll
    for (int di = 0; di < 3; ++di)
      #pragma unroll
      for (int dj = 0; dj < 3; ++dj)
        acc += w9[di*3+dj] * ti[ii+di][jj+dj];
    toutT[jj][ii] = f2b(acc);
  }
  __syncthreads();
  #pragma unroll
  for (int q = 0; q < 16; ++q){
    int jj = (tid >> 6)*16 + q;
    out[(long long)b*262144 + (j0+jj)*512 + i0 + (tid & 63)] = toutT[jj][tid & 63];
  }
}

// ---------- depthwise 3x3; Hbuf (b,n,c) bf16 -> T1 (b,n,c) bf16 ----------
__global__ __launch_bounds__(256) void dwconv_k(const bf16* __restrict__ H2, bf16* __restrict__ T1,
                                                const bf16* __restrict__ w, const bf16* __restrict__ bias){
  int p = blockIdx.x*256 + threadIdx.x;
  int cp = p & 255;
  int n = (p >> 8) & 1023;
  int b = p >> 18;
  int c0 = cp*2;
  int wi = n >> 5, hg = n & 31;
  float a0 = b2f(bias[c0]), a1 = b2f(bias[c0+1]);
  #pragma unroll
  for (int di = 0; di < 3; ++di){
    int gw = wi + di - 1;
    if ((unsigned)gw >= 32u) continue;
    #pragma unroll
    for (int dj = 0; dj < 3; ++dj){
      int gh = hg + dj - 1;
      if ((unsigned)gh >= 32u) continue;
      unsigned hv = *(const unsigned*)&H2[((long long)b*1024 + (gw*32+gh))*512 + c0];
      float w0 = b2f(w[c0*9 + di*3 + dj]);
      float w1 = b2f(w[(c0+1)*9 + di*3 + dj]);
      a0 += w0 * bits2f(hv & 0xffffu);
      a1 += w1 * bits2f(hv >> 16);
    }
  }
  bf16 h0 = f2b(a0), h1 = f2b(a1);
  unsigned o = ((unsigned)*(unsigned short*)&h1 << 16) | (unsigned)*(unsigned short*)&h0;
  *(unsigned*)&T1[((long long)b*1024 + n)*512 + c0] = o;
}

// ---------- fold pw bias + BN(eval), all layers ----------
__global__ void bnaff_all_k(const bf16* __restrict__ pwb, const bf16* __restrict__ g,
                            const bf16* __restrict__ bb, const bf16* __restrict__ m,
                            const bf16* __restrict__ v, float* __restrict__ BNAFF){
  int l = blockIdx.x, o = threadIdx.x;
  float s = b2f(g[l*256+o]) * rsqrtf(b2f(v[l*256+o]) + 1e-5f);
  BNAFF[l*512 + o] = s;
  BNAFF[l*512 + 256 + o] = (b2f(pwb[l*256+o]) - b2f(m[l*256+o])) * s + b2f(bb[l*256+o]);
}

// ---------- HbufT[b][c][n] = Hbuf[b][n][c] ----------
__global__ __launch_bounds__(256) void htrans_k(const bf16* __restrict__ Hb, bf16* __restrict__ HT){
  __shared__ bf16 t[64][65];
  int b = blockIdx.z;
  int n0 = blockIdx.x*64, c0 = blockIdx.y*64;
  int lane = threadIdx.x & 63, quad = threadIdx.x >> 6;
  #pragma unroll
  for (int k = 0; k < 16; ++k){
    int r = quad*16 + k;
    t[r][lane] = Hb[((long long)b*1024 + n0 + r)*512 + c0 + lane];
  }
  __syncthreads();
  #pragma unroll
  for (int k = 0; k < 16; ++k){
    int c = quad*16 + k;
    HT[(long long)b*524288 + (long long)(c0+c)*1024 + n0 + lane] = t[lane][c];
  }
}

// ---------- orchestration ----------
extern "C" void kernel_launch(void* const* d_in, const int* in_sizes, int n_in,
                              void* d_out, int out_size, void* d_ws, size_t ws_size,
                              hipStream_t stream)
{
  (void)in_sizes; (void)n_in; (void)out_size;

  const bool big = ws_size >= 207000000ull;
  const long long ATTN_SZ = big ? 33554432LL : 8388608LL;

  // ---- arena ----
  float* X     = (float*)d_ws;
  bf16*  WBsm  = (bf16*)(X + 2097152);
  bf16*  WqkvT = WBsm  + 2139648;
  bf16*  WoutT = WqkvT + 3145728;
  bf16*  WqsT  = WoutT + 1048576;
  bf16*  Hbuf  = WqsT  + 8388608;
  bf16*  HbufT = Hbuf  + 2097152;
  bf16*  QKV   = HbufT + 2097152;
  bf16*  Vt    = QKV   + 6291456;
  bf16*  OUTH  = Vt    + 2097152;
  bf16*  OUT   = OUTH  + 2097152;
  bf16*  ATTN  = OUT   + 2097152;
  bf16*  ATTNC = ATTN  + ATTN_SZ;
  float* BNAFF = (float*)(ATTNC + ATTN_SZ);
  bf16*  WR    = (bf16*)(BNAFF + 2048);
  float* SROW  = (float*)(WR + 6144);
  float* SSROW = SROW + 32768;
  int*   FLAG  = (int*)(SSROW + 2048);

  float* ASPEC   = (float*)OUTH;
  bf16*  ASPECCT = ATTNC;
  bf16*  T1 = ATTN;
  bf16*  T3 = ATTN + 2097152;
  bf16*  T2 = ATTNC + 2097152;
  bf16*  SQK = ATTN;

  // ---- small-weight arena ----
  static const int widx[21] = {1,2,5,6,7,9,10,11,12,13,14,15,16,17,18,19,20,21,22,23,24};
  static const long long wsz[21] = {2048,2048,2048,2304,32,36,4,2048,2048,18432,2048,
                                    524288,1024,1024,1024,1024,1024,524288,2048,1048576,2048};
  WCvt21 wc;
  long long cum = 0;
  bf16* wp[21];
  for (int t = 0; t < 21; ++t){
    wc.src[t] = d_in[widx[t]];
    wc.cum[t] = cum;
    wp[t] = WBsm + cum;
    cum += wsz[t];
  }
  wc.cum[21] = cum;

  bf16 *w_ln1w = wp[0],  *w_ln1b = wp[1],  *w_bout = wp[2],  *w_spw = wp[3];
  bf16 *w_spb  = wp[4],  *w_specw= wp[5],  *w_specb= wp[6],  *w_ln2w= wp[7];
  bf16 *w_ln2b = wp[8],  *w_dww  = wp[9],  *w_dwb  = wp[10], *w_pww = wp[11];
  bf16 *w_pwb  = wp[12], *w_bng  = wp[13], *w_bnb  = wp[14], *w_bnm = wp[15];
  bf16 *w_bnv  = wp[16], *w_c1w  = wp[17], *w_c1b  = wp[18], *w_c2w = wp[19];
  bf16 *w_c2b  = wp[20];

  // ---- setup ----
  detect_k<<<1, 256, 0, stream>>>((const unsigned*)d_in[0], FLAG);
  cvt_x_k<<<8192, 256, 0, stream>>>(d_in[0], X, FLAG);
  cvt_w_k<<<(int)((cum + 255)/256), 256, 0, stream>>>(wc, WBsm, cum, FLAG);
  wtrans_k<<<dim3(8,24,4), 256, 0, stream>>>(d_in[3], WqkvT, 1536, 512, 786432LL, 786432LL, FLAG);
  wtrans_k<<<dim3(8, 8,4), 256, 0, stream>>>(d_in[4], WoutT,  512, 512, 262144LL, 262144LL, FLAG);
  wtrans_k<<<dim3(16,32,4),256, 0, stream>>>(d_in[8], WqsT,  3072,1024, 3145728LL,2097152LL, FLAG);
  bnaff_all_k<<<4, 256, 0, stream>>>(w_pwb, w_bng, w_bnb, w_bnm, w_bnv, BNAFF);
  wprep_k<<<4, 256, 0, stream>>>(w_spw, WR);

  for (int l = 0; l < 4; ++l){
    zero_k<<<136, 256, 0, stream>>>(SROW, 34816);
    // --- spatial attention ---
    ln_k<<<4096, 256, 0, stream>>>(X, Hbuf, w_ln1w + l*512, w_ln1b + l*512);
    gmfma<2,4,bf16>(stream, 1, 4096, 1536, 512,
        Hbuf, 512, 0, WqkvT + (long long)l*786432, 512, 0, QKV, 1536, 0,
        1.f, 0, nullptr, nullptr, nullptr, nullptr, 0, Vt);
    if (big){
      // srow index = h*szl + b*szh + i*sgm = h + b*8192 + i*8
      gmfma_exp<4,4,bf16>(stream, 32, 1024, 1024, 64,
          QKV, 1536, 64, 1572864, QKV + 512, 1536, 64, 1572864,
          ATTN, 1024, 1048576, 8388608, 0.125f,
          SROW, 1, 8192, 8);
      convNorm_k<<<dim3(2,128,4), 256, 0, stream>>>(ATTN, ATTNC, WR + l*1536, w_spb + l*8,
                                                    SROW, 8388608LL);
      gmfma_x<1,1,bf16>(stream, 32, 1024, 64, 1024,
          ATTNC, 1024, 1048576, 8388608, Vt, 1024, 65536, 524288,
          OUTH, 512, 64, 524288);
    } else {
      for (int b = 0; b < 4; ++b){
        bf16* qkvb = QKV + (long long)b*1572864;
        gmfma_exp<4,4,bf16>(stream, 8, 1024, 1024, 64,
            qkvb, 1536, 64, 8*64, qkvb + 512, 1536, 64, 8*64,
            ATTN, 1024, 1048576, 8*1048576, 0.125f,
            SROW + b*8192, 1, 0, 8);
        convNorm_k<<<dim3(2,128,1), 256, 0, stream>>>(ATTN, ATTNC, WR + l*1536, w_spb + l*8,
                                                      SROW + b*8192, 8388608LL);
        gmfma<1,1,bf16>(stream, 8, 1024, 64, 1024,
            ATTNC, 1024, 1048576, Vt + (long long)b*524288, 1024, 65536,
            OUTH + (long long)b*524288, 512, 64);
      }
    }
    gmfma<1,1,bf16>(stream, 1, 4096, 512, 512,
        OUTH, 512, 0, WoutT + (long long)l*262144, 512, 0, OUT, 512, 0,
        1.f, 0, w_bout + l*512);
    // --- spectral attention ---
    htrans_k<<<dim3(16,8,4), 256, 0, stream>>>(Hbuf, HbufT);
    gmfma<2,2,bf16>(stream, 4, 512, 2048, 1024,
        HbufT, 1024, 524288, WqsT + (long long)l*2097152, 1024, 0, SQK, 2048, 1048576);
    gmfma_exp<1,1,float>(stream, 4, 512, 512, 1024,
        SQK, 2048, 1048576, 8*1048576, SQK + 1024, 2048, 1048576, 8*1048576,
        ASPEC, 512, 262144, 8*262144, 0.125f,
        SSROW, 512, 0, 1);
    conv_spec_k<<<dim3(8,8,4), 256, 0, stream>>>(ASPEC, ASPECCT, w_specw + l*9, w_specb + l,
                                                 SSROW);
    gmfma<1,1,float>(stream, 4, 1024, 512, 512,
        OUT, 512, 524288, ASPECCT, 512, 262144, X, 512, 524288, 1.f, 1);
    // --- conv FFN ---
    ln_k<<<4096, 256, 0, stream>>>(X, Hbuf, w_ln2w + l*512, w_ln2b + l*512);
    dwconv_k<<<4096, 256, 0, stream>>>(Hbuf, T1, w_dww + l*4608, w_dwb + l*512);
    gmfma<1,1,bf16>(stream, 4, 1024, 256, 512,
        T1, 512, 524288, w_pww + (long long)l*131072, 512, 0, T2, 256, 262144,
        1.f, 0, nullptr, BNAFF + l*512, BNAFF + l*512 + 256);
    gmfma<1,1,bf16>(stream, 4, 1024, 512, 256,
        T2, 256, 262144, w_c1w + (long long)l*131072, 256, 0, T3, 512, 524288,
        1.f, 0, w_c1b + l*512, nullptr, nullptr, nullptr, 1);
    gmfma<1,1,float>(stream, 4, 1024, 512, 512,
        T3, 512, 524288, w_c2w + (long long)l*262144, 512, 0, X, 512, 524288,
        1.f, 1, w_c2b + l*512, nullptr, nullptr, Hbuf, 1);
  }

  store_out_k<<<8192, 256, 0, stream>>>(X, d_out, FLAG);
}